// Round 1
// baseline (594.679 us; speedup 1.0000x reference)
//
#include <hip/hip_runtime.h>
#include <math.h>

#define SS 256
#define HH 256
#define MLEN 1000
#define CWW 16
#define NOC 16
#define RSTR 17

// float-indexed workspace offsets
#define WS_X      0u          // [2048][256]
#define WS_H      524288u     // [2048][256]
#define WS_V1     1048576u    // [2048][256]
#define WS_V2     1572864u    // [2048][256]
#define WS_ST     2097152u    // [2048][256]
#define WS_CP     2621440u    // [8][3][256][16]
#define WS_CV     2719744u    // [8][256][16]
#define WS_EK     2752512u    // [8][256]
#define WS_SK     2754560u    // [8][256]
#define WS_ALPHA  2756608u    // [8]
#define WS_MELI   2756616u    // [8] (int bits)
#define WS_TMASK  2756624u    // [8][256]  1.0 = masked

// output offsets (flat float buffer, tuple concat)
#define OUT_UP    0u
#define OUT_W     2048000u
#define OUT_ALPHA 4096000u
#define OUT_MLEN  4096008u
#define OUT_MMASK 4096016u

// ---------------- text_mask canonicalization (layout-adaptive) ----------------
__global__ __launch_bounds__(256) void k_mask(const void* __restrict__ traw, float* __restrict__ ws){
  __shared__ int s_fu, s_ff, s_nz;
  const unsigned char* mb=(const unsigned char*)traw;
  const unsigned int*  mw=(const unsigned int*)traw;
  int tid=threadIdx.x;
  if(tid==0){s_fu=0;s_ff=0;s_nz=0;}
  __syncthreads();
  int fu=0,ff=0,nz=0;
  for(int w=tid;w<512;w+=256){           // first 2048 bytes only (safe for all layouts)
    unsigned int v=mw[w];
    if(v){ nz=1; if(v==0x3F800000u) ff=1; else if(v&0xFFFFFF00u) fu=1; }
  }
  if(fu) atomicOr(&s_fu,1);
  if(ff) atomicOr(&s_ff,1);
  if(nz) atomicOr(&s_nz,1);
  __syncthreads();
  // word-per-element if float-1.0 words seen, or nonzero words but no packed bytes.
  int words = (s_ff || (!s_fu && s_nz));
  for(int i=tid;i<2048;i+=256){
    unsigned int v = words ? mw[i] : (unsigned int)mb[i];
    ws[WS_TMASK+i] = v ? 1.0f : 0.0f;
  }
}

// ---------------- input projection: concat(ce,spk) @ in_w + in_b -> x ----------------
__global__ __launch_bounds__(256) void k_inproj(const float* __restrict__ ce, const float* __restrict__ spk,
    const float* __restrict__ in_w, const float* __restrict__ in_b, float* __restrict__ ws){
  __shared__ float A[8][SS];
  int m0=blockIdx.x*8, tid=threadIdx.x, b=m0>>8;
  for(int r=0;r<8;r++){
    int m=m0+r;
    A[r][tid] = (tid<192) ? ce[m*192+tid] : spk[b*64+tid-192];
  }
  __syncthreads();
  float acc[8]; float bn=in_b[tid];
  #pragma unroll
  for(int r=0;r<8;r++) acc[r]=bn;
  for(int k=0;k<SS;k+=4){
    float w0=in_w[(k+0)*HH+tid], w1=in_w[(k+1)*HH+tid];
    float w2=in_w[(k+2)*HH+tid], w3=in_w[(k+3)*HH+tid];
    #pragma unroll
    for(int r=0;r<8;r++){
      float4 a4=*(const float4*)&A[r][k];
      acc[r]+=a4.x*w0+a4.y*w1+a4.z*w2+a4.w*w3;
    }
  }
  for(int r=0;r<8;r++) ws[WS_X+(unsigned)(m0+r)*HH+tid]=acc[r];
}

// ---------------- LN + GLU projection + sigmoid gate + mask ----------------
__global__ __launch_bounds__(256) void k_glu(const float* __restrict__ xin,
    const float* __restrict__ glu_w, const float* __restrict__ glu_b,
    const float* __restrict__ lgam, const float* __restrict__ lbet,
    const float* __restrict__ tmask, float* __restrict__ hout){
  __shared__ float A[8][SS];
  __shared__ float mrs[8][2];
  int m0=blockIdx.x*8, tid=threadIdx.x;
  int wid=tid>>6, lane=tid&63;
  for(int r=0;r<8;r++) A[r][tid]=xin[(m0+r)*HH+tid];
  __syncthreads();
  for(int rr=0;rr<2;rr++){
    int r=wid*2+rr;
    float x0=A[r][lane],x1=A[r][lane+64],x2=A[r][lane+128],x3=A[r][lane+192];
    float s=x0+x1+x2+x3, q=x0*x0+x1*x1+x2*x2+x3*x3;
    for(int off=32;off;off>>=1){ s+=__shfl_down(s,off); q+=__shfl_down(q,off); }
    if(lane==0){ float mean=s*(1.0f/HH); float var=q*(1.0f/HH)-mean*mean;
      mrs[r][0]=mean; mrs[r][1]=rsqrtf(var+1e-5f); }
  }
  __syncthreads();
  float g=lgam[tid], be=lbet[tid];
  #pragma unroll
  for(int r=0;r<8;r++) A[r][tid]=(A[r][tid]-mrs[r][0])*mrs[r][1]*g+be;
  __syncthreads();
  float acca[8], accg[8];
  float ba=glu_b[tid], bg=glu_b[tid+HH];
  #pragma unroll
  for(int r=0;r<8;r++){acca[r]=ba;accg[r]=bg;}
  for(int k=0;k<HH;k+=4){
    float wa0=glu_w[(k+0)*512+tid],   wg0=glu_w[(k+0)*512+tid+HH];
    float wa1=glu_w[(k+1)*512+tid],   wg1=glu_w[(k+1)*512+tid+HH];
    float wa2=glu_w[(k+2)*512+tid],   wg2=glu_w[(k+2)*512+tid+HH];
    float wa3=glu_w[(k+3)*512+tid],   wg3=glu_w[(k+3)*512+tid+HH];
    #pragma unroll
    for(int r=0;r<8;r++){
      float4 a4=*(const float4*)&A[r][k];
      acca[r]+=a4.x*wa0+a4.y*wa1+a4.z*wa2+a4.w*wa3;
      accg[r]+=a4.x*wg0+a4.y*wg1+a4.z*wg2+a4.w*wg3;
    }
  }
  for(int r=0;r<8;r++){
    int m=m0+r;
    float hv=acca[r]*(1.0f/(1.0f+expf(-accg[r])));
    hout[m*HH+tid]=(tmask[m]!=0.0f)?0.0f:hv;
  }
}

// ---------------- depthwise conv + out proj + residual + mask ----------------
__global__ __launch_bounds__(256) void k_dwout(const float* __restrict__ hin, const float* __restrict__ resid,
    const float* __restrict__ dw, const float* __restrict__ out_w, const float* __restrict__ out_b,
    const float* __restrict__ tmask, float* __restrict__ vout){
  __shared__ float Ht[10][SS];
  __shared__ float A[8][SS];
  __shared__ float dws[3][SS];
  int m0=blockIdx.x*8, tid=threadIdx.x, b=m0>>8, s0=m0&255;
  for(int rr=0;rr<10;rr++){
    int s=s0-1+rr;
    Ht[rr][tid]=(s>=0&&s<SS)?hin[(b*SS+s)*HH+tid]:0.0f;
  }
  {
    float d0=dw[tid*3],d1=dw[tid*3+1],d2=dw[tid*3+2];
    float mx=fmaxf(d0,fmaxf(d1,d2));
    float e0=expf(d0-mx),e1=expf(d1-mx),e2=expf(d2-mx);
    float inv=1.0f/(e0+e1+e2);
    dws[0][tid]=e0*inv; dws[1][tid]=e1*inv; dws[2][tid]=e2*inv;
  }
  __syncthreads();
  for(int r=0;r<8;r++)
    A[r][tid]=dws[0][tid]*Ht[r][tid]+dws[1][tid]*Ht[r+1][tid]+dws[2][tid]*Ht[r+2][tid];
  __syncthreads();
  float acc[8]; float bn=out_b[tid];
  #pragma unroll
  for(int r=0;r<8;r++) acc[r]=bn;
  for(int k=0;k<HH;k+=4){
    float w0=out_w[(k+0)*HH+tid], w1=out_w[(k+1)*HH+tid];
    float w2=out_w[(k+2)*HH+tid], w3=out_w[(k+3)*HH+tid];
    #pragma unroll
    for(int r=0;r<8;r++){
      float4 a4=*(const float4*)&A[r][k];
      acc[r]+=a4.x*w0+a4.y*w1+a4.z*w2+a4.w*w3;
    }
  }
  for(int r=0;r<8;r++){
    int m=m0+r;
    float v=acc[r]+resid[m*HH+tid];
    vout[m*HH+tid]=(tmask[m]!=0.0f)?0.0f:v;
  }
}

// ---------------- duration head: D, alpha, cumsum, mel_len, masks ----------------
__global__ __launch_bounds__(256) void k_dur(const float* __restrict__ V2, const float* __restrict__ p1w,
    const float* __restrict__ p1b, const float* __restrict__ sdo, const float* __restrict__ rhythm,
    float* __restrict__ ws, float* __restrict__ outp){
  __shared__ float p1[HH];
  __shared__ float sd[SS];
  __shared__ float red[16];
  int b=blockIdx.x, tid=threadIdx.x;
  int wid=tid>>6, lane=tid&63;
  p1[tid]=p1w[tid];
  __syncthreads();
  float accd=p1b[0];
  const float* row=V2+(unsigned)(b*SS+tid)*HH;
  for(int k=0;k<HH;k+=4){
    float4 v=*(const float4*)&row[k];
    accd+=v.x*p1[k]+v.y*p1[k+1]+v.z*p1[k+2]+v.w*p1[k+3];
  }
  float Dv=fmaxf(accd,0.0f)+log1pf(expf(-fabsf(accd)));   // stable softplus
  if(ws[WS_TMASK+b*SS+tid]!=0.0f) Dv=0.0f;
  float sv=sdo[b*SS+tid];
  float a=Dv, c=sv;
  for(int off=32;off;off>>=1){ a+=__shfl_down(a,off); c+=__shfl_down(c,off); }
  if(lane==0){ red[wid]=a; red[wid+8]=c; }
  __syncthreads();
  float Dsum=red[0]+red[1]+red[2]+red[3];
  float pred=red[8]+red[9]+red[10]+red[11];
  float al=(pred/rhythm[b])/Dsum;
  float sDv=al*Dv;
  sd[tid]=sDv;
  __syncthreads();
  for(int off=1;off<SS;off<<=1){
    float t=(tid>=off)?sd[tid-off]:0.0f;
    __syncthreads();
    sd[tid]+=t;
    __syncthreads();
  }
  float ek=sd[tid], sk=ek-sDv;
  ws[WS_EK+b*SS+tid]=ek;
  ws[WS_SK+b*SS+tid]=sk;
  float melf=sd[SS-1];
  int mel=(int)rintf(melf); mel=mel<1?1:(mel>MLEN?MLEN:mel);
  if(tid==0){
    ws[WS_ALPHA+b]=al;
    ((int*)ws)[WS_MELI+b]=mel;
    outp[OUT_ALPHA+b]=al;
    outp[OUT_MLEN+b]=(float)mel;
  }
  for(int t=tid;t<MLEN;t+=SS) outp[OUT_MMASK+b*MLEN+t]=(t>=mel)?1.0f:0.0f;
}

// ---------------- T = conv1d(V,p2)+b ; sT = alpha*T ----------------
__global__ __launch_bounds__(256) void k_T(const float* __restrict__ V2, const float* __restrict__ p2k,
    const float* __restrict__ p2b, const float* __restrict__ ws){
  __shared__ float Vt[10][SS];
  int m0=blockIdx.x*8, tid=threadIdx.x, b=m0>>8, s0=m0&255;
  float* wsm=(float*)ws;
  for(int rr=0;rr<10;rr++){
    int s=s0-1+rr;
    Vt[rr][tid]=(s>=0&&s<SS)?V2[(b*SS+s)*HH+tid]:0.0f;
  }
  __syncthreads();
  float acc[8]; float bn=p2b[tid];
  #pragma unroll
  for(int r=0;r<8;r++) acc[r]=bn;
  for(int k3=0;k3<3;k3++){
    const float* w=p2k+(unsigned)k3*HH*HH;
    for(int k=0;k<HH;k+=4){
      float w0=w[(k+0)*HH+tid], w1=w[(k+1)*HH+tid];
      float w2=w[(k+2)*HH+tid], w3=w[(k+3)*HH+tid];
      #pragma unroll
      for(int r=0;r<8;r++){
        float4 a4=*(const float4*)&Vt[r+k3][k];
        acc[r]+=a4.x*w0+a4.y*w1+a4.z*w2+a4.w*w3;
      }
    }
  }
  float al=wsm[WS_ALPHA+b];
  for(int r=0;r<8;r++) wsm[WS_ST+(unsigned)(m0+r)*HH+tid]=al*acc[r];
}

// ---------------- Cv = LN16(relu(conv1d(alpha*V, cw)+cwb)) ----------------
__global__ __launch_bounds__(256) void k_cv(const float* __restrict__ V2, const float* __restrict__ cwk,
    const float* __restrict__ cwb, const float* __restrict__ cwg, const float* __restrict__ cwbe,
    float* __restrict__ ws){
  __shared__ float Vt[18][SS];
  int b=blockIdx.x>>4, tile=blockIdx.x&15, tid=threadIdx.x;
  int sbase=tile*16;
  float al=ws[WS_ALPHA+b];
  for(int rr=0;rr<18;rr++){
    int s=sbase-1+rr;
    Vt[rr][tid]=(s>=0&&s<SS)?al*V2[(b*SS+s)*HH+tid]:0.0f;
  }
  __syncthreads();
  int sl=tid>>4, oc=tid&15;
  float a0=cwb[oc],a1=0.f,a2=0.f,a3=0.f;
  for(int k3=0;k3<3;k3++){
    const float* vp=&Vt[sl+k3][0];
    const float* wpp=cwk+(unsigned)k3*HH*CWW+oc;
    for(int c=0;c<HH;c+=4){
      a0+=vp[c+0]*wpp[(c+0)*CWW];
      a1+=vp[c+1]*wpp[(c+1)*CWW];
      a2+=vp[c+2]*wpp[(c+2)*CWW];
      a3+=vp[c+3]*wpp[(c+3)*CWW];
    }
  }
  float acc=fmaxf((a0+a1)+(a2+a3),0.0f);
  float ssum=acc, qsum=acc*acc;
  for(int off=8;off;off>>=1){ ssum+=__shfl_xor(ssum,off); qsum+=__shfl_xor(qsum,off); }
  float mean=ssum*(1.0f/CWW), var=qsum*(1.0f/CWW)-mean*mean;
  float cv=(acc-mean)*rsqrtf(var+1e-5f)*cwg[oc]+cwbe[oc];
  ws[WS_CV+(unsigned)(b*SS+sbase+sl)*CWW+oc]=cv;
}

// ---------------- CP[b][dt][s][oc]: t-invariant Cv contribution to conv1 ----------------
__global__ __launch_bounds__(256) void k_cp(const float* __restrict__ mkb1k, float* __restrict__ ws){
  __shared__ float CvL[258][RSTR];
  __shared__ float k1c[3][3][CWW][NOC];
  int b=blockIdx.x, tid=threadIdx.x;
  for(int i=tid;i<3*3*CWW*NOC;i+=256){
    int oc=i&15, ic=(i>>4)&15, kk=i>>8;
    int kw=kk%3, kh=kk/3;
    k1c[kh][kw][ic][oc]=mkb1k[((kh*3+kw)*18+2+ic)*NOC+oc];
  }
  for(int i=tid;i<SS*CWW;i+=256) CvL[1+(i>>4)][i&15]=ws[WS_CV+(unsigned)b*SS*CWW+i];
  if(tid<CWW){ CvL[0][tid]=0.f; CvL[257][tid]=0.f; }
  __syncthreads();
  float* cpg=ws+WS_CP+(unsigned)b*3*SS*NOC;
  for(int dt=0;dt<3;dt++){
    float acc[NOC];
    #pragma unroll
    for(int oc=0;oc<NOC;oc++) acc[oc]=0.f;
    #pragma unroll
    for(int ds=0;ds<3;ds++){
      #pragma unroll
      for(int ic=0;ic<CWW;ic++){
        float v=CvL[tid+ds][ic];
        #pragma unroll
        for(int oc=0;oc<NOC;oc++) acc[oc]+=v*k1c[dt][ds][ic][oc];
      }
    }
    for(int oc=0;oc<NOC;oc++) cpg[(unsigned)(dt*SS+tid)*NOC+oc]=acc[oc];
  }
}

// ---------------- stage B: conv1(light) -> conv2 -> softmax -> Wmat -> up -> LN ----------------
__global__ __launch_bounds__(256,2) void k_stageB(
    const float* __restrict__ ws, const float* __restrict__ mkb1k, const float* __restrict__ mkb1b,
    const float* __restrict__ mkb2k, const float* __restrict__ mkb2b,
    const float* __restrict__ lww, const float* __restrict__ lwb,
    const float* __restrict__ lng, const float* __restrict__ lnb,
    float* __restrict__ outp){
  __shared__ float ring[3][258][RSTR];   // silu(conv1) rows, s-halo
  __shared__ float skL[258], ekL[258], finL[258];
  __shared__ float Wch[8][SS];
  __shared__ float red[16];
  __shared__ float mrs[8][2];
  int bx=blockIdx.x, b=bx/125, chunk=bx%125, t0=chunk*8, tid=threadIdx.x;
  int wid=tid>>6, lane=tid&63;
  if(tid<258){
    float sk=0.f, ek=0.f, fin=0.f;
    if(tid>=1 && tid<=SS){
      sk=ws[WS_SK+b*SS+tid-1];
      ek=ws[WS_EK+b*SS+tid-1];
      fin=(ws[WS_TMASK+b*SS+tid-1]!=0.0f)?0.0f:1.0f;
    }
    skL[tid]=sk; ekL[tid]=ek; finL[tid]=fin;
  }
  if(tid<3*RSTR){ int rr=tid/RSTR, c=tid%RSTR; ring[rr][0][c]=0.f; ring[rr][257][c]=0.f; }
  int mel=((const int*)ws)[WS_MELI+b];
  __syncthreads();

  const float* cpb=ws+WS_CP+(unsigned)b*3*SS*NOC;

  auto conv1row=[&](int T){
    int s=tid;
    float acc[NOC];
    #pragma unroll
    for(int oc=0;oc<NOC;oc++) acc[oc]=mkb1b[oc];
    #pragma unroll
    for(int dt=0;dt<3;dt++){
      int tr=T+dt-1;
      if(tr<0||tr>=MLEN) continue;
      bool valid=(tr<mel);
      float tt=(float)(tr+1);
      float gg[3], hh[3];
      #pragma unroll
      for(int ds=0;ds<3;ds++){
        int j=s+ds;
        float f = valid ? ((j>=1&&j<=SS)?1.0f:0.0f) : finL[j];
        gg[ds]=f*(tt-skL[j]);
        hh[ds]=f*(ekL[j]-tt);
      }
      const float* cpr=cpb+(unsigned)(dt*SS+s)*NOC;
      float4 c0=((const float4*)cpr)[0], c1=((const float4*)cpr)[1];
      float4 c2=((const float4*)cpr)[2], c3=((const float4*)cpr)[3];
      acc[0]+=c0.x; acc[1]+=c0.y; acc[2]+=c0.z; acc[3]+=c0.w;
      acc[4]+=c1.x; acc[5]+=c1.y; acc[6]+=c1.z; acc[7]+=c1.w;
      acc[8]+=c2.x; acc[9]+=c2.y; acc[10]+=c2.z; acc[11]+=c2.w;
      acc[12]+=c3.x; acc[13]+=c3.y; acc[14]+=c3.z; acc[15]+=c3.w;
      #pragma unroll
      for(int ds=0;ds<3;ds++){
        const float* kA=mkb1k+((dt*3+ds)*18+0)*NOC;
        const float* kB=mkb1k+((dt*3+ds)*18+1)*NOC;
        #pragma unroll
        for(int oc=0;oc<NOC;oc++) acc[oc]+=gg[ds]*kA[oc]+hh[ds]*kB[oc];
      }
    }
    int slot=T%3;
    #pragma unroll
    for(int oc=0;oc<NOC;oc++){
      float x=acc[oc];
      ring[slot][s+1][oc]=x/(1.0f+__expf(-x));
    }
  };

  if(t0>0) conv1row(t0-1);
  conv1row(t0);

  #pragma unroll 1
  for(int r=0;r<8;r++){
    int t=t0+r;
    if(t+1<MLEN) conv1row(t+1);
    __syncthreads();
    // conv2 at row t
    float a2[NOC];
    #pragma unroll
    for(int oc=0;oc<NOC;oc++) a2[oc]=mkb2b[oc];
    int s=tid;
    #pragma unroll
    for(int dt=0;dt<3;dt++){
      int tr=t+dt-1;
      if(tr<0||tr>=MLEN) continue;
      int slot=tr%3;
      #pragma unroll
      for(int ds=0;ds<3;ds++){
        const float* rp=&ring[slot][s+ds][0];
        const float* kp=mkb2k+((dt*3+ds)*NOC)*NOC;
        #pragma unroll
        for(int ic=0;ic<NOC;ic++){
          float v=rp[ic];
          #pragma unroll
          for(int oc=0;oc<NOC;oc++) a2[oc]+=v*kp[ic*NOC+oc];
        }
      }
    }
    float wsc=lwb[0];
    #pragma unroll
    for(int oc=0;oc<NOC;oc++){
      float x=a2[oc];
      wsc+=(x/(1.0f+__expf(-x)))*lww[oc];
    }
    // masked softmax over s (mask = text only; attn|text == text)
    float fm=finL[tid+1];
    float val=(fm!=0.0f)?wsc:-3.0e38f;
    float mx=val;
    for(int off=32;off;off>>=1) mx=fmaxf(mx,__shfl_down(mx,off));
    if(lane==0) red[wid]=mx;
    __syncthreads();
    mx=fmaxf(fmaxf(red[0],red[1]),fmaxf(red[2],red[3]));
    float e=(fm!=0.0f)?__expf(wsc-mx):0.0f;
    float sm=e;
    for(int off=32;off;off>>=1) sm+=__shfl_down(sm,off);
    if(lane==0) red[8+wid]=sm;
    __syncthreads();
    sm=red[8]+red[9]+red[10]+red[11];
    float wv=e/sm;
    Wch[r][tid]=wv;
    outp[OUT_W+(unsigned)(b*MLEN+t)*SS+tid]=wv;
    __syncthreads();   // guards ring slot reuse + red reuse
  }

  // up chunk: up[r][h] = sum_s Wch[r][s]*sT[b][s][h]
  float up[8];
  #pragma unroll
  for(int r=0;r<8;r++) up[r]=0.f;
  const float* sTb=ws+WS_ST+(unsigned)b*SS*HH+tid;
  #pragma unroll 2
  for(int s4=0;s4<SS;s4+=4){
    float v0=sTb[(s4+0)*HH], v1=sTb[(s4+1)*HH], v2=sTb[(s4+2)*HH], v3=sTb[(s4+3)*HH];
    #pragma unroll
    for(int r=0;r<8;r++){
      float4 w4=*(const float4*)&Wch[r][s4];
      up[r]+=w4.x*v0+w4.y*v1+w4.z*v2+w4.w*v3;
    }
  }
  __syncthreads();
  #pragma unroll
  for(int r=0;r<8;r++) Wch[r][tid]=up[r];
  __syncthreads();
  for(int rr=0;rr<2;rr++){
    int r=wid*2+rr;
    float x0=Wch[r][lane],x1=Wch[r][lane+64],x2=Wch[r][lane+128],x3=Wch[r][lane+192];
    float s1=x0+x1+x2+x3, q1=x0*x0+x1*x1+x2*x2+x3*x3;
    for(int off=32;off;off>>=1){ s1+=__shfl_down(s1,off); q1+=__shfl_down(q1,off); }
    if(lane==0){
      float mean=s1*(1.0f/HH);
      float var=q1*(1.0f/HH)-mean*mean;
      mrs[r][0]=mean; mrs[r][1]=rsqrtf(var+1e-5f);
    }
  }
  __syncthreads();
  float gg=lng[tid], bb=lnb[tid];
  #pragma unroll
  for(int r=0;r<8;r++){
    int t=t0+r;
    float v=(t<mel)?((up[r]-mrs[r][0])*mrs[r][1]*gg+bb):0.0f;
    outp[OUT_UP+(unsigned)(b*MLEN+t)*SS+tid]=v;
  }
}

extern "C" void kernel_launch(void* const* d_in, const int* in_sizes, int n_in,
                              void* d_out, int out_size, void* d_ws, size_t ws_size,
                              hipStream_t stream){
  const float* ce   =(const float*)d_in[0];
  const float* spk  =(const float*)d_in[1];
  const float* rhy  =(const float*)d_in[2];
  const float* sdo  =(const float*)d_in[3];
  const void*  tmr  =d_in[4];
  const float* in_w =(const float*)d_in[5];
  const float* in_b =(const float*)d_in[6];
  const float* l0lg =(const float*)d_in[7];
  const float* l0lb =(const float*)d_in[8];
  const float* l0gw =(const float*)d_in[9];
  const float* l0gb =(const float*)d_in[10];
  const float* l0dw =(const float*)d_in[11];
  const float* l0ow =(const float*)d_in[12];
  const float* l0ob =(const float*)d_in[13];
  const float* l1lg =(const float*)d_in[14];
  const float* l1lb =(const float*)d_in[15];
  const float* l1gw =(const float*)d_in[16];
  const float* l1gb =(const float*)d_in[17];
  const float* l1dw =(const float*)d_in[18];
  const float* l1ow =(const float*)d_in[19];
  const float* l1ob =(const float*)d_in[20];
  const float* p1w  =(const float*)d_in[21];
  const float* p1b  =(const float*)d_in[22];
  const float* p2k  =(const float*)d_in[23];
  const float* p2b  =(const float*)d_in[24];
  const float* cwk  =(const float*)d_in[25];
  const float* cwb  =(const float*)d_in[26];
  const float* cwg  =(const float*)d_in[27];
  const float* cwbe =(const float*)d_in[28];
  const float* m1k  =(const float*)d_in[29];
  const float* m1b  =(const float*)d_in[30];
  const float* m2k  =(const float*)d_in[31];
  const float* m2b  =(const float*)d_in[32];
  const float* lww  =(const float*)d_in[33];
  const float* lwbp =(const float*)d_in[34];
  const float* lng  =(const float*)d_in[35];
  const float* lnb  =(const float*)d_in[36];
  float* ws=(float*)d_ws;
  float* outp=(float*)d_out;

  k_mask  <<<1,256,0,stream>>>(tmr, ws);
  k_inproj<<<256,256,0,stream>>>(ce, spk, in_w, in_b, ws);
  k_glu   <<<256,256,0,stream>>>(ws+WS_X,  l0gw, l0gb, l0lg, l0lb, ws+WS_TMASK, ws+WS_H);
  k_dwout <<<256,256,0,stream>>>(ws+WS_H,  ws+WS_X,  l0dw, l0ow, l0ob, ws+WS_TMASK, ws+WS_V1);
  k_glu   <<<256,256,0,stream>>>(ws+WS_V1, l1gw, l1gb, l1lg, l1lb, ws+WS_TMASK, ws+WS_H);
  k_dwout <<<256,256,0,stream>>>(ws+WS_H,  ws+WS_V1, l1dw, l1ow, l1ob, ws+WS_TMASK, ws+WS_V2);
  k_dur   <<<8,256,0,stream>>>(ws+WS_V2, p1w, p1b, sdo, rhy, ws, outp);
  k_T     <<<256,256,0,stream>>>(ws+WS_V2, p2k, p2b, ws);
  k_cv    <<<128,256,0,stream>>>(ws+WS_V2, cwk, cwb, cwg, cwbe, ws);
  k_cp    <<<8,256,0,stream>>>(m1k, ws);
  k_stageB<<<1000,256,0,stream>>>(ws, m1k, m1b, m2k, m2b, lww, lwbp, lng, lnb, outp);
}

// Round 2
// 473.372 us; speedup vs baseline: 1.2563x; 1.2563x over previous
//
#include <hip/hip_runtime.h>
#include <math.h>

#define SS 256
#define HH 256
#define MLEN 1000
#define CWW 16
#define NOC 16
#define RB 24          // ring row stride in bf16 elems (48B, 16B-aligned)

typedef __attribute__((ext_vector_type(8))) short bfrag;
typedef __attribute__((ext_vector_type(4))) float ffrag;

// float-indexed workspace offsets
#define WS_X      0u          // [2048][256]
#define WS_H      524288u     // [2048][256]
#define WS_V1     1048576u    // [2048][256]
#define WS_V2     1572864u    // [2048][256]
#define WS_ST     2097152u    // [2048][256]
#define WS_CP     2621440u    // [8][3][256][16]
#define WS_CV     2719744u    // [8][256][16]
#define WS_EK     2752512u    // [8][256]
#define WS_SK     2754560u    // [8][256]
#define WS_ALPHA  2756608u    // [8]
#define WS_MELI   2756616u    // [8] (int bits)
#define WS_TMASK  2756624u    // [8][256]  1.0 = masked

// output offsets (flat float buffer, tuple concat)
#define OUT_UP    0u
#define OUT_W     2048000u
#define OUT_ALPHA 4096000u
#define OUT_MLEN  4096008u
#define OUT_MMASK 4096016u

__device__ __forceinline__ unsigned bf16rne(float x){
  unsigned u=__float_as_uint(x);
  u += 0x7fffu + ((u>>16)&1u);
  return u;
}

// ---------------- text_mask canonicalization (layout-adaptive) ----------------
__global__ __launch_bounds__(256) void k_mask(const void* __restrict__ traw, float* __restrict__ ws){
  __shared__ int s_fu, s_ff, s_nz;
  const unsigned char* mb=(const unsigned char*)traw;
  const unsigned int*  mw=(const unsigned int*)traw;
  int tid=threadIdx.x;
  if(tid==0){s_fu=0;s_ff=0;s_nz=0;}
  __syncthreads();
  int fu=0,ff=0,nz=0;
  for(int w=tid;w<512;w+=256){
    unsigned int v=mw[w];
    if(v){ nz=1; if(v==0x3F800000u) ff=1; else if(v&0xFFFFFF00u) fu=1; }
  }
  if(fu) atomicOr(&s_fu,1);
  if(ff) atomicOr(&s_ff,1);
  if(nz) atomicOr(&s_nz,1);
  __syncthreads();
  int words = (s_ff || (!s_fu && s_nz));
  for(int i=tid;i<2048;i+=256){
    unsigned int v = words ? mw[i] : (unsigned int)mb[i];
    ws[WS_TMASK+i] = v ? 1.0f : 0.0f;
  }
}

// ---------------- input projection: concat(ce,spk) @ in_w + in_b -> x ----------------
__global__ __launch_bounds__(256) void k_inproj(const float* __restrict__ ce, const float* __restrict__ spk,
    const float* __restrict__ in_w, const float* __restrict__ in_b, float* __restrict__ ws){
  __shared__ float A[8][SS];
  int m0=blockIdx.x*8, tid=threadIdx.x, b=m0>>8;
  for(int r=0;r<8;r++){
    int m=m0+r;
    A[r][tid] = (tid<192) ? ce[m*192+tid] : spk[b*64+tid-192];
  }
  __syncthreads();
  float acc[8]; float bn=in_b[tid];
  #pragma unroll
  for(int r=0;r<8;r++) acc[r]=bn;
  for(int k=0;k<SS;k+=4){
    float w0=in_w[(k+0)*HH+tid], w1=in_w[(k+1)*HH+tid];
    float w2=in_w[(k+2)*HH+tid], w3=in_w[(k+3)*HH+tid];
    #pragma unroll
    for(int r=0;r<8;r++){
      float4 a4=*(const float4*)&A[r][k];
      acc[r]+=a4.x*w0+a4.y*w1+a4.z*w2+a4.w*w3;
    }
  }
  for(int r=0;r<8;r++) ws[WS_X+(unsigned)(m0+r)*HH+tid]=acc[r];
}

// ---------------- LN + GLU projection + sigmoid gate + mask ----------------
__global__ __launch_bounds__(256) void k_glu(const float* __restrict__ xin,
    const float* __restrict__ glu_w, const float* __restrict__ glu_b,
    const float* __restrict__ lgam, const float* __restrict__ lbet,
    const float* __restrict__ tmask, float* __restrict__ hout){
  __shared__ float A[8][SS];
  __shared__ float mrs[8][2];
  int m0=blockIdx.x*8, tid=threadIdx.x;
  int wid=tid>>6, lane=tid&63;
  for(int r=0;r<8;r++) A[r][tid]=xin[(m0+r)*HH+tid];
  __syncthreads();
  for(int rr=0;rr<2;rr++){
    int r=wid*2+rr;
    float x0=A[r][lane],x1=A[r][lane+64],x2=A[r][lane+128],x3=A[r][lane+192];
    float s=x0+x1+x2+x3, q=x0*x0+x1*x1+x2*x2+x3*x3;
    for(int off=32;off;off>>=1){ s+=__shfl_down(s,off); q+=__shfl_down(q,off); }
    if(lane==0){ float mean=s*(1.0f/HH); float var=q*(1.0f/HH)-mean*mean;
      mrs[r][0]=mean; mrs[r][1]=rsqrtf(var+1e-5f); }
  }
  __syncthreads();
  float g=lgam[tid], be=lbet[tid];
  #pragma unroll
  for(int r=0;r<8;r++) A[r][tid]=(A[r][tid]-mrs[r][0])*mrs[r][1]*g+be;
  __syncthreads();
  float acca[8], accg[8];
  float ba=glu_b[tid], bg=glu_b[tid+HH];
  #pragma unroll
  for(int r=0;r<8;r++){acca[r]=ba;accg[r]=bg;}
  for(int k=0;k<HH;k+=4){
    float wa0=glu_w[(k+0)*512+tid],   wg0=glu_w[(k+0)*512+tid+HH];
    float wa1=glu_w[(k+1)*512+tid],   wg1=glu_w[(k+1)*512+tid+HH];
    float wa2=glu_w[(k+2)*512+tid],   wg2=glu_w[(k+2)*512+tid+HH];
    float wa3=glu_w[(k+3)*512+tid],   wg3=glu_w[(k+3)*512+tid+HH];
    #pragma unroll
    for(int r=0;r<8;r++){
      float4 a4=*(const float4*)&A[r][k];
      acca[r]+=a4.x*wa0+a4.y*wa1+a4.z*wa2+a4.w*wa3;
      accg[r]+=a4.x*wg0+a4.y*wg1+a4.z*wg2+a4.w*wg3;
    }
  }
  for(int r=0;r<8;r++){
    int m=m0+r;
    float hv=acca[r]*(1.0f/(1.0f+expf(-accg[r])));
    hout[m*HH+tid]=(tmask[m]!=0.0f)?0.0f:hv;
  }
}

// ---------------- depthwise conv + out proj + residual + mask ----------------
__global__ __launch_bounds__(256) void k_dwout(const float* __restrict__ hin, const float* __restrict__ resid,
    const float* __restrict__ dw, const float* __restrict__ out_w, const float* __restrict__ out_b,
    const float* __restrict__ tmask, float* __restrict__ vout){
  __shared__ float Ht[10][SS];
  __shared__ float A[8][SS];
  __shared__ float dws[3][SS];
  int m0=blockIdx.x*8, tid=threadIdx.x, b=m0>>8, s0=m0&255;
  for(int rr=0;rr<10;rr++){
    int s=s0-1+rr;
    Ht[rr][tid]=(s>=0&&s<SS)?hin[(b*SS+s)*HH+tid]:0.0f;
  }
  {
    float d0=dw[tid*3],d1=dw[tid*3+1],d2=dw[tid*3+2];
    float mx=fmaxf(d0,fmaxf(d1,d2));
    float e0=expf(d0-mx),e1=expf(d1-mx),e2=expf(d2-mx);
    float inv=1.0f/(e0+e1+e2);
    dws[0][tid]=e0*inv; dws[1][tid]=e1*inv; dws[2][tid]=e2*inv;
  }
  __syncthreads();
  for(int r=0;r<8;r++)
    A[r][tid]=dws[0][tid]*Ht[r][tid]+dws[1][tid]*Ht[r+1][tid]+dws[2][tid]*Ht[r+2][tid];
  __syncthreads();
  float acc[8]; float bn=out_b[tid];
  #pragma unroll
  for(int r=0;r<8;r++) acc[r]=bn;
  for(int k=0;k<HH;k+=4){
    float w0=out_w[(k+0)*HH+tid], w1=out_w[(k+1)*HH+tid];
    float w2=out_w[(k+2)*HH+tid], w3=out_w[(k+3)*HH+tid];
    #pragma unroll
    for(int r=0;r<8;r++){
      float4 a4=*(const float4*)&A[r][k];
      acc[r]+=a4.x*w0+a4.y*w1+a4.z*w2+a4.w*w3;
    }
  }
  for(int r=0;r<8;r++){
    int m=m0+r;
    float v=acc[r]+resid[m*HH+tid];
    vout[m*HH+tid]=(tmask[m]!=0.0f)?0.0f:v;
  }
}

// ---------------- duration head: D, alpha, cumsum, mel_len, masks ----------------
__global__ __launch_bounds__(256) void k_dur(const float* __restrict__ V2, const float* __restrict__ p1w,
    const float* __restrict__ p1b, const float* __restrict__ sdo, const float* __restrict__ rhythm,
    float* __restrict__ ws, float* __restrict__ outp){
  __shared__ float p1[HH];
  __shared__ float sd[SS];
  __shared__ float red[16];
  int b=blockIdx.x, tid=threadIdx.x;
  int wid=tid>>6, lane=tid&63;
  p1[tid]=p1w[tid];
  __syncthreads();
  float accd=p1b[0];
  const float* row=V2+(unsigned)(b*SS+tid)*HH;
  for(int k=0;k<HH;k+=4){
    float4 v=*(const float4*)&row[k];
    accd+=v.x*p1[k]+v.y*p1[k+1]+v.z*p1[k+2]+v.w*p1[k+3];
  }
  float Dv=fmaxf(accd,0.0f)+log1pf(expf(-fabsf(accd)));   // stable softplus
  if(ws[WS_TMASK+b*SS+tid]!=0.0f) Dv=0.0f;
  float sv=sdo[b*SS+tid];
  float a=Dv, c=sv;
  for(int off=32;off;off>>=1){ a+=__shfl_down(a,off); c+=__shfl_down(c,off); }
  if(lane==0){ red[wid]=a; red[wid+8]=c; }
  __syncthreads();
  float Dsum=red[0]+red[1]+red[2]+red[3];
  float pred=red[8]+red[9]+red[10]+red[11];
  float al=(pred/rhythm[b])/Dsum;
  float sDv=al*Dv;
  sd[tid]=sDv;
  __syncthreads();
  for(int off=1;off<SS;off<<=1){
    float t=(tid>=off)?sd[tid-off]:0.0f;
    __syncthreads();
    sd[tid]+=t;
    __syncthreads();
  }
  float ek=sd[tid], sk=ek-sDv;
  ws[WS_EK+b*SS+tid]=ek;
  ws[WS_SK+b*SS+tid]=sk;
  float melf=sd[SS-1];
  int mel=(int)rintf(melf); mel=mel<1?1:(mel>MLEN?MLEN:mel);
  if(tid==0){
    ws[WS_ALPHA+b]=al;
    ((int*)ws)[WS_MELI+b]=mel;
    outp[OUT_ALPHA+b]=al;
    outp[OUT_MLEN+b]=(float)mel;
  }
  for(int t=tid;t<MLEN;t+=SS) outp[OUT_MMASK+b*MLEN+t]=(t>=mel)?1.0f:0.0f;
}

// ---------------- T = conv1d(V,p2)+b ; sT = alpha*T ----------------
__global__ __launch_bounds__(256) void k_T(const float* __restrict__ V2, const float* __restrict__ p2k,
    const float* __restrict__ p2b, const float* __restrict__ ws){
  __shared__ float Vt[10][SS];
  int m0=blockIdx.x*8, tid=threadIdx.x, b=m0>>8, s0=m0&255;
  float* wsm=(float*)ws;
  for(int rr=0;rr<10;rr++){
    int s=s0-1+rr;
    Vt[rr][tid]=(s>=0&&s<SS)?V2[(b*SS+s)*HH+tid]:0.0f;
  }
  __syncthreads();
  float acc[8]; float bn=p2b[tid];
  #pragma unroll
  for(int r=0;r<8;r++) acc[r]=bn;
  for(int k3=0;k3<3;k3++){
    const float* w=p2k+(unsigned)k3*HH*HH;
    for(int k=0;k<HH;k+=4){
      float w0=w[(k+0)*HH+tid], w1=w[(k+1)*HH+tid];
      float w2=w[(k+2)*HH+tid], w3=w[(k+3)*HH+tid];
      #pragma unroll
      for(int r=0;r<8;r++){
        float4 a4=*(const float4*)&Vt[r+k3][k];
        acc[r]+=a4.x*w0+a4.y*w1+a4.z*w2+a4.w*w3;
      }
    }
  }
  float al=wsm[WS_ALPHA+b];
  for(int r=0;r<8;r++) wsm[WS_ST+(unsigned)(m0+r)*HH+tid]=al*acc[r];
}

// ---------------- Cv = LN16(relu(conv1d(alpha*V, cw)+cwb)) ----------------
__global__ __launch_bounds__(256) void k_cv(const float* __restrict__ V2, const float* __restrict__ cwk,
    const float* __restrict__ cwb, const float* __restrict__ cwg, const float* __restrict__ cwbe,
    float* __restrict__ ws){
  __shared__ float Vt[18][SS];
  int b=blockIdx.x>>4, tile=blockIdx.x&15, tid=threadIdx.x;
  int sbase=tile*16;
  float al=ws[WS_ALPHA+b];
  for(int rr=0;rr<18;rr++){
    int s=sbase-1+rr;
    Vt[rr][tid]=(s>=0&&s<SS)?al*V2[(b*SS+s)*HH+tid]:0.0f;
  }
  __syncthreads();
  int sl=tid>>4, oc=tid&15;
  float a0=cwb[oc],a1=0.f,a2=0.f,a3=0.f;
  for(int k3=0;k3<3;k3++){
    const float* vp=&Vt[sl+k3][0];
    const float* wpp=cwk+(unsigned)k3*HH*CWW+oc;
    for(int c=0;c<HH;c+=4){
      a0+=vp[c+0]*wpp[(c+0)*CWW];
      a1+=vp[c+1]*wpp[(c+1)*CWW];
      a2+=vp[c+2]*wpp[(c+2)*CWW];
      a3+=vp[c+3]*wpp[(c+3)*CWW];
    }
  }
  float acc=fmaxf((a0+a1)+(a2+a3),0.0f);
  float ssum=acc, qsum=acc*acc;
  for(int off=8;off;off>>=1){ ssum+=__shfl_xor(ssum,off); qsum+=__shfl_xor(qsum,off); }
  float mean=ssum*(1.0f/CWW), var=qsum*(1.0f/CWW)-mean*mean;
  float cv=(acc-mean)*rsqrtf(var+1e-5f)*cwg[oc]+cwbe[oc];
  ws[WS_CV+(unsigned)(b*SS+sbase+sl)*CWW+oc]=cv;
}

// ---------------- CP[b][dt][s][oc]: t-invariant Cv contribution to conv1 ----------------
__global__ __launch_bounds__(256) void k_cp(const float* __restrict__ mkb1k, float* __restrict__ ws){
  __shared__ float CvL[258][17];
  __shared__ float k1c[3][3][CWW][NOC];
  int b=blockIdx.x, tid=threadIdx.x;
  for(int i=tid;i<3*3*CWW*NOC;i+=256){
    int oc=i&15, ic=(i>>4)&15, kk=i>>8;
    int kw=kk%3, kh=kk/3;
    k1c[kh][kw][ic][oc]=mkb1k[((kh*3+kw)*18+2+ic)*NOC+oc];
  }
  for(int i=tid;i<SS*CWW;i+=256) CvL[1+(i>>4)][i&15]=ws[WS_CV+(unsigned)b*SS*CWW+i];
  if(tid<CWW){ CvL[0][tid]=0.f; CvL[257][tid]=0.f; }
  __syncthreads();
  float* cpg=ws+WS_CP+(unsigned)b*3*SS*NOC;
  for(int dt=0;dt<3;dt++){
    float acc[NOC];
    #pragma unroll
    for(int oc=0;oc<NOC;oc++) acc[oc]=0.f;
    #pragma unroll
    for(int ds=0;ds<3;ds++){
      #pragma unroll
      for(int ic=0;ic<CWW;ic++){
        float v=CvL[tid+ds][ic];
        #pragma unroll
        for(int oc=0;oc<NOC;oc++) acc[oc]+=v*k1c[dt][ds][ic][oc];
      }
    }
    for(int oc=0;oc<NOC;oc++) cpg[(unsigned)(dt*SS+tid)*NOC+oc]=acc[oc];
  }
}

// ---------------- stage B: conv1(VALU) -> conv2(bf16 MFMA) -> softmax -> Wmat -> up -> LN ----------------
__global__ __launch_bounds__(256,2) void k_stageB(
    const float* __restrict__ ws, const float* __restrict__ mkb1k, const float* __restrict__ mkb1b,
    const float* __restrict__ mkb2k, const float* __restrict__ mkb2b,
    const float* __restrict__ lww, const float* __restrict__ lwb,
    const float* __restrict__ lng, const float* __restrict__ lnb,
    float* __restrict__ outp){
  __shared__ short ringh[3][258][RB];     // silu(conv1) rows in bf16, s-halo; 37.2 KB
  __shared__ float skL[258], ekL[258], finL[258];
  __shared__ float Wch[8][SS];
  __shared__ float wscL[SS];
  __shared__ float red[16];
  __shared__ float mrs[8][2];
  int bx=blockIdx.x, b=bx/125, chunk=bx%125, t0=chunk*8, tid=threadIdx.x;
  int wid=tid>>6, lane=tid&63;
  int lq=lane>>4, lm=lane&15;
  if(tid<258){
    float sk=0.f, ek=0.f, fin=0.f;
    if(tid>=1 && tid<=SS){
      sk=ws[WS_SK+b*SS+tid-1];
      ek=ws[WS_EK+b*SS+tid-1];
      fin=(ws[WS_TMASK+b*SS+tid-1]!=0.0f)?0.0f:1.0f;
    }
    skL[tid]=sk; ekL[tid]=ek; finL[tid]=fin;
  }
  // zero ring pad rows (row 0 and 257 of each slot): 3*2*12 = 72 ints
  if(tid<72){
    int sl=tid/24, rem=tid%24;
    int row=(rem<12)?0:257, c=(rem%12)*2;
    *(int*)&ringh[sl][row][c]=0;
  }
  int mel=((const int*)ws)[WS_MELI+b];
  __syncthreads();

  const float* cpb=ws+WS_CP+(unsigned)b*3*SS*NOC;

  // ---- per-lane MFMA constants for conv2 ----
  // K ordering: k = dt*48 + ds*16 + ic  (matches mkb2k flat layout); 5 K-steps of 32.
  // a_frag elem j = A[m=lm][k=lq*8+j]; b_frag elem j = B[k=lq*8+j][n=lm]; D: row=lq*4+reg, col=lm.
  unsigned offA[5]; int dtL[5], zgL[5];
  bfrag bfw[5];
  {
    #pragma unroll
    for(int i=0;i<5;i++){
      int g=4*i+lq;
      int dt,ds,hf,zg;
      if(g<18){ dt=g/6; int rm=g-6*dt; ds=rm>>1; hf=rm&1; zg=0; }
      else { dt=0; ds=0; hf=0; zg=1; }
      int srow=wid*64+lm+ds;          // tile 0; +tt*16 handled via imm offset
      offA[i]=(unsigned)((srow*RB+8*hf)*2);
      dtL[i]=dt; zgL[i]=zg;
      int pk[4];
      if(!zg){
        #pragma unroll
        for(int j=0;j<4;j++){
          unsigned u0=bf16rne(mkb2k[(8*g+2*j)*NOC+lm]);
          unsigned u1=bf16rne(mkb2k[(8*g+2*j+1)*NOC+lm]);
          pk[j]=(int)((u0>>16)|(u1&0xffff0000u));
        }
      } else pk[0]=pk[1]=pk[2]=pk[3]=0;
      bfw[i]=__builtin_bit_cast(bfrag, make_int4(pk[0],pk[1],pk[2],pk[3]));
    }
  }
  float b2v=mkb2b[lm];
  float lwwv=lww[lm];
  float lwb0=lwb[0];
  const char* ringB=(const char*)&ringh[0][0][0];
  bfrag azero={};

  auto conv1row=[&](int T){
    int s=tid;
    float acc[NOC];
    #pragma unroll
    for(int oc=0;oc<NOC;oc++) acc[oc]=mkb1b[oc];
    #pragma unroll
    for(int dt=0;dt<3;dt++){
      int tr=T+dt-1;
      if(tr<0||tr>=MLEN) continue;
      bool valid=(tr<mel);
      float tt=(float)(tr+1);
      float gg[3], hh[3];
      #pragma unroll
      for(int ds=0;ds<3;ds++){
        int j=s+ds;
        float f = valid ? ((j>=1&&j<=SS)?1.0f:0.0f) : finL[j];
        gg[ds]=f*(tt-skL[j]);
        hh[ds]=f*(ekL[j]-tt);
      }
      const float* cpr=cpb+(unsigned)(dt*SS+s)*NOC;
      float4 c0=((const float4*)cpr)[0], c1=((const float4*)cpr)[1];
      float4 c2=((const float4*)cpr)[2], c3=((const float4*)cpr)[3];
      acc[0]+=c0.x; acc[1]+=c0.y; acc[2]+=c0.z; acc[3]+=c0.w;
      acc[4]+=c1.x; acc[5]+=c1.y; acc[6]+=c1.z; acc[7]+=c1.w;
      acc[8]+=c2.x; acc[9]+=c2.y; acc[10]+=c2.z; acc[11]+=c2.w;
      acc[12]+=c3.x; acc[13]+=c3.y; acc[14]+=c3.z; acc[15]+=c3.w;
      #pragma unroll
      for(int ds=0;ds<3;ds++){
        const float* kA=mkb1k+((dt*3+ds)*18+0)*NOC;
        const float* kB=mkb1k+((dt*3+ds)*18+1)*NOC;
        #pragma unroll
        for(int oc=0;oc<NOC;oc++) acc[oc]+=gg[ds]*kA[oc]+hh[ds]*kB[oc];
      }
    }
    int slot=T%3;
    int pk[8];
    #pragma unroll
    for(int j=0;j<8;j++){
      float x0=acc[2*j], x1=acc[2*j+1];
      float s0=x0/(1.0f+__expf(-x0));
      float s1=x1/(1.0f+__expf(-x1));
      unsigned u0=bf16rne(s0), u1=bf16rne(s1);
      pk[j]=(int)((u0>>16)|(u1&0xffff0000u));
    }
    int4* dst=(int4*)&ringh[slot][s+1][0];
    dst[0]=make_int4(pk[0],pk[1],pk[2],pk[3]);
    dst[1]=make_int4(pk[4],pk[5],pk[6],pk[7]);
  };

  if(t0>0) conv1row(t0-1);
  conv1row(t0);

  #pragma unroll 1
  for(int r=0;r<8;r++){
    int t=t0+r;
    if(t+1<MLEN) conv1row(t+1);
    __syncthreads();            // ring slots (t-1,t,t+1) ready
    // ---- conv2 via MFMA ----
    int tmod=t%3;
    ffrag acc2[4];
    #pragma unroll
    for(int tt=0;tt<4;tt++){ acc2[tt][0]=b2v; acc2[tt][1]=b2v; acc2[tt][2]=b2v; acc2[tt][3]=b2v; }
    #pragma unroll
    for(int i=0;i<5;i++){
      int dt=dtL[i];
      int x=tmod+dt+2; x=(x>=3)?x-3:x; x=(x>=3)?x-3:x;   // slot=(t+dt-1) mod 3
      int tr=t+dt-1;
      bool av=((unsigned)tr<(unsigned)MLEN)&&(!zgL[i]);
      const char* rp=ringB+(unsigned)x*(258u*RB*2u)+offA[i];
      #pragma unroll
      for(int tt=0;tt<4;tt++){
        int4 ra=*(const int4*)(rp+tt*(16*RB*2));
        bfrag a=av?__builtin_bit_cast(bfrag,ra):azero;
        acc2[tt]=__builtin_amdgcn_mfma_f32_16x16x32_bf16(a,bfw[i],acc2[tt],0,0,0);
      }
    }
    // silu -> dot lww -> reduce over oc (lanes lm 0..15 of each quarter)
    #pragma unroll
    for(int tt=0;tt<4;tt++){
      float out4[4];
      #pragma unroll
      for(int q=0;q<4;q++){
        float xx=acc2[tt][q];
        float pv=(xx/(1.0f+__expf(-xx)))*lwwv;
        pv+=__shfl_xor(pv,1); pv+=__shfl_xor(pv,2); pv+=__shfl_xor(pv,4); pv+=__shfl_xor(pv,8);
        out4[q]=pv+lwb0;
      }
      if(lm==0){
        *(float4*)&wscL[wid*64+tt*16+lq*4]=make_float4(out4[0],out4[1],out4[2],out4[3]);
      }
    }
    __syncthreads();            // wscL ready
    // ---- masked softmax over s ----
    float fm=finL[tid+1];
    float wsc=wscL[tid];
    float val=(fm!=0.0f)?wsc:-3.0e38f;
    float mx=val;
    for(int off=32;off;off>>=1) mx=fmaxf(mx,__shfl_down(mx,off));
    if(lane==0) red[wid]=mx;
    __syncthreads();
    mx=fmaxf(fmaxf(red[0],red[1]),fmaxf(red[2],red[3]));
    float e=(fm!=0.0f)?__expf(wsc-mx):0.0f;
    float sm=e;
    for(int off=32;off;off>>=1) sm+=__shfl_down(sm,off);
    if(lane==0) red[8+wid]=sm;
    __syncthreads();
    sm=red[8]+red[9]+red[10]+red[11];
    float wv=e/sm;
    Wch[r][tid]=wv;
    outp[OUT_W+(unsigned)(b*MLEN+t)*SS+tid]=wv;
    __syncthreads();            // guards ring slot reuse + red/wscL reuse
  }

  // up chunk: up[r][h] = sum_s Wch[r][s]*sT[b][s][h]
  float up[8];
  #pragma unroll
  for(int r=0;r<8;r++) up[r]=0.f;
  const float* sTb=ws+WS_ST+(unsigned)b*SS*HH+tid;
  #pragma unroll 2
  for(int s4=0;s4<SS;s4+=4){
    float v0=sTb[(s4+0)*HH], v1=sTb[(s4+1)*HH], v2=sTb[(s4+2)*HH], v3=sTb[(s4+3)*HH];
    #pragma unroll
    for(int r=0;r<8;r++){
      float4 w4=*(const float4*)&Wch[r][s4];
      up[r]+=w4.x*v0+w4.y*v1+w4.z*v2+w4.w*v3;
    }
  }
  __syncthreads();
  #pragma unroll
  for(int r=0;r<8;r++) Wch[r][tid]=up[r];
  __syncthreads();
  for(int rr=0;rr<2;rr++){
    int r=wid*2+rr;
    float x0=Wch[r][lane],x1=Wch[r][lane+64],x2=Wch[r][lane+128],x3=Wch[r][lane+192];
    float s1=x0+x1+x2+x3, q1=x0*x0+x1*x1+x2*x2+x3*x3;
    for(int off=32;off;off>>=1){ s1+=__shfl_down(s1,off); q1+=__shfl_down(q1,off); }
    if(lane==0){
      float mean=s1*(1.0f/HH);
      float var=q1*(1.0f/HH)-mean*mean;
      mrs[r][0]=mean; mrs[r][1]=rsqrtf(var+1e-5f);
    }
  }
  __syncthreads();
  float gg=lng[tid], bb=lnb[tid];
  #pragma unroll
  for(int r=0;r<8;r++){
    int t=t0+r;
    float v=(t<mel)?((up[r]-mrs[r][0])*mrs[r][1]*gg+bb):0.0f;
    outp[OUT_UP+(unsigned)(b*MLEN+t)*SS+tid]=v;
  }
}

extern "C" void kernel_launch(void* const* d_in, const int* in_sizes, int n_in,
                              void* d_out, int out_size, void* d_ws, size_t ws_size,
                              hipStream_t stream){
  const float* ce   =(const float*)d_in[0];
  const float* spk  =(const float*)d_in[1];
  const float* rhy  =(const float*)d_in[2];
  const float* sdo  =(const float*)d_in[3];
  const void*  tmr  =d_in[4];
  const float* in_w =(const float*)d_in[5];
  const float* in_b =(const float*)d_in[6];
  const float* l0lg =(const float*)d_in[7];
  const float* l0lb =(const float*)d_in[8];
  const float* l0gw =(const float*)d_in[9];
  const float* l0gb =(const float*)d_in[10];
  const float* l0dw =(const float*)d_in[11];
  const float* l0ow =(const float*)d_in[12];
  const float* l0ob =(const float*)d_in[13];
  const float* l1lg =(const float*)d_in[14];
  const float* l1lb =(const float*)d_in[15];
  const float* l1gw =(const float*)d_in[16];
  const float* l1gb =(const float*)d_in[17];
  const float* l1dw =(const float*)d_in[18];
  const float* l1ow =(const float*)d_in[19];
  const float* l1ob =(const float*)d_in[20];
  const float* p1w  =(const float*)d_in[21];
  const float* p1b  =(const float*)d_in[22];
  const float* p2k  =(const float*)d_in[23];
  const float* p2b  =(const float*)d_in[24];
  const float* cwk  =(const float*)d_in[25];
  const float* cwb  =(const float*)d_in[26];
  const float* cwg  =(const float*)d_in[27];
  const float* cwbe =(const float*)d_in[28];
  const float* m1k  =(const float*)d_in[29];
  const float* m1b  =(const float*)d_in[30];
  const float* m2k  =(const float*)d_in[31];
  const float* m2b  =(const float*)d_in[32];
  const float* lww  =(const float*)d_in[33];
  const float* lwbp =(const float*)d_in[34];
  const float* lng  =(const float*)d_in[35];
  const float* lnb  =(const float*)d_in[36];
  float* ws=(float*)d_ws;
  float* outp=(float*)d_out;

  k_mask  <<<1,256,0,stream>>>(tmr, ws);
  k_inproj<<<256,256,0,stream>>>(ce, spk, in_w, in_b, ws);
  k_glu   <<<256,256,0,stream>>>(ws+WS_X,  l0gw, l0gb, l0lg, l0lb, ws+WS_TMASK, ws+WS_H);
  k_dwout <<<256,256,0,stream>>>(ws+WS_H,  ws+WS_X,  l0dw, l0ow, l0ob, ws+WS_TMASK, ws+WS_V1);
  k_glu   <<<256,256,0,stream>>>(ws+WS_V1, l1gw, l1gb, l1lg, l1lb, ws+WS_TMASK, ws+WS_H);
  k_dwout <<<256,256,0,stream>>>(ws+WS_H,  ws+WS_V1, l1dw, l1ow, l1ob, ws+WS_TMASK, ws+WS_V2);
  k_dur   <<<8,256,0,stream>>>(ws+WS_V2, p1w, p1b, sdo, rhy, ws, outp);
  k_T     <<<256,256,0,stream>>>(ws+WS_V2, p2k, p2b, ws);
  k_cv    <<<128,256,0,stream>>>(ws+WS_V2, cwk, cwb, cwg, cwbe, ws);
  k_cp    <<<8,256,0,stream>>>(m1k, ws);
  k_stageB<<<1000,256,0,stream>>>(ws, m1k, m1b, m2k, m2b, lww, lwbp, lng, lnb, outp);
}

// Round 3
// 449.136 us; speedup vs baseline: 1.3241x; 1.0540x over previous
//
#include <hip/hip_runtime.h>
#include <math.h>

#define SS 256
#define HH 256
#define MLEN 1000
#define CWW 16
#define NOC 16
#define RB 24          // ring row stride in bf16 elems (48B, 16B-aligned)

typedef __attribute__((ext_vector_type(8))) short bfrag;
typedef __attribute__((ext_vector_type(4))) float ffrag;

// float-indexed workspace offsets
#define WS_CCV    0u          // [8][256][16]  (reuses dead WS_X region)
#define WS_SSV    32768u
#define WS_CCI    65536u
#define WS_SSI    98304u
#define WS_X      131072u     // [2048][256]  input-proj x (shifted; 0.5M floats free above tables? no: X needs 524288)
// NOTE: X placed at 131072..655359; H at 655360..1179647; V1,V2 follow.
#define WS_H      655360u     // [2048][256]; after k_dwout#2 reused as sTt (bf16 [8][256][256] = 1MB)
#define WS_V1     1179648u
#define WS_V2     1703936u
#define WS_CP     2228224u    // [8][3][256][16]
#define WS_CV     2326528u    // [8][256][16]
#define WS_EK     2359296u    // [8][256]
#define WS_SK     2361344u    // [8][256]
#define WS_ALPHA  2363392u    // [8]
#define WS_MELI   2363400u    // [8] (int bits)
#define WS_TMASK  2363408u    // [8][256]  1.0 = masked

// output offsets (flat float buffer, tuple concat)
#define OUT_UP    0u
#define OUT_W     2048000u
#define OUT_ALPHA 4096000u
#define OUT_MLEN  4096008u
#define OUT_MMASK 4096016u

__device__ __forceinline__ unsigned bf16rne(float x){
  unsigned u=__float_as_uint(x);
  u += 0x7fffu + ((u>>16)&1u);
  return u;
}

// ---------------- text_mask canonicalization (layout-adaptive) ----------------
__global__ __launch_bounds__(256) void k_mask(const void* __restrict__ traw, float* __restrict__ ws){
  __shared__ int s_fu, s_ff, s_nz;
  const unsigned char* mb=(const unsigned char*)traw;
  const unsigned int*  mw=(const unsigned int*)traw;
  int tid=threadIdx.x;
  if(tid==0){s_fu=0;s_ff=0;s_nz=0;}
  __syncthreads();
  int fu=0,ff=0,nz=0;
  for(int w=tid;w<512;w+=256){
    unsigned int v=mw[w];
    if(v){ nz=1; if(v==0x3F800000u) ff=1; else if(v&0xFFFFFF00u) fu=1; }
  }
  if(fu) atomicOr(&s_fu,1);
  if(ff) atomicOr(&s_ff,1);
  if(nz) atomicOr(&s_nz,1);
  __syncthreads();
  int words = (s_ff || (!s_fu && s_nz));
  for(int i=tid;i<2048;i+=256){
    unsigned int v = words ? mw[i] : (unsigned int)mb[i];
    ws[WS_TMASK+i] = v ? 1.0f : 0.0f;
  }
}

// ---------------- input projection: concat(ce,spk) @ in_w + in_b -> x ----------------
__global__ __launch_bounds__(256) void k_inproj(const float* __restrict__ ce, const float* __restrict__ spk,
    const float* __restrict__ in_w, const float* __restrict__ in_b, float* __restrict__ ws){
  __shared__ float A[4][SS];
  int m0=blockIdx.x*4, tid=threadIdx.x, b=m0>>8;
  for(int r=0;r<4;r++){
    int m=m0+r;
    A[r][tid] = (tid<192) ? ce[m*192+tid] : spk[b*64+tid-192];
  }
  __syncthreads();
  float acc[4]; float bn=in_b[tid];
  #pragma unroll
  for(int r=0;r<4;r++) acc[r]=bn;
  for(int k=0;k<SS;k+=4){
    float w0=in_w[(k+0)*HH+tid], w1=in_w[(k+1)*HH+tid];
    float w2=in_w[(k+2)*HH+tid], w3=in_w[(k+3)*HH+tid];
    #pragma unroll
    for(int r=0;r<4;r++){
      float4 a4=*(const float4*)&A[r][k];
      acc[r]+=a4.x*w0+a4.y*w1+a4.z*w2+a4.w*w3;
    }
  }
  for(int r=0;r<4;r++) ws[WS_X+(unsigned)(m0+r)*HH+tid]=acc[r];
}

// ---------------- LN + GLU projection + sigmoid gate + mask ----------------
__global__ __launch_bounds__(256) void k_glu(const float* __restrict__ xin,
    const float* __restrict__ glu_w, const float* __restrict__ glu_b,
    const float* __restrict__ lgam, const float* __restrict__ lbet,
    const float* __restrict__ tmask, float* __restrict__ hout){
  __shared__ float A[4][SS];
  __shared__ float mrs[4][2];
  int m0=blockIdx.x*4, tid=threadIdx.x;
  int wid=tid>>6, lane=tid&63;
  for(int r=0;r<4;r++) A[r][tid]=xin[(m0+r)*HH+tid];
  __syncthreads();
  {
    int r=wid;
    float x0=A[r][lane],x1=A[r][lane+64],x2=A[r][lane+128],x3=A[r][lane+192];
    float s=x0+x1+x2+x3, q=x0*x0+x1*x1+x2*x2+x3*x3;
    for(int off=32;off;off>>=1){ s+=__shfl_down(s,off); q+=__shfl_down(q,off); }
    if(lane==0){ float mean=s*(1.0f/HH); float var=q*(1.0f/HH)-mean*mean;
      mrs[r][0]=mean; mrs[r][1]=rsqrtf(var+1e-5f); }
  }
  __syncthreads();
  float g=lgam[tid], be=lbet[tid];
  #pragma unroll
  for(int r=0;r<4;r++) A[r][tid]=(A[r][tid]-mrs[r][0])*mrs[r][1]*g+be;
  __syncthreads();
  float acca[4], accg[4];
  float ba=glu_b[tid], bg=glu_b[tid+HH];
  #pragma unroll
  for(int r=0;r<4;r++){acca[r]=ba;accg[r]=bg;}
  for(int k=0;k<HH;k+=4){
    float wa0=glu_w[(k+0)*512+tid],   wg0=glu_w[(k+0)*512+tid+HH];
    float wa1=glu_w[(k+1)*512+tid],   wg1=glu_w[(k+1)*512+tid+HH];
    float wa2=glu_w[(k+2)*512+tid],   wg2=glu_w[(k+2)*512+tid+HH];
    float wa3=glu_w[(k+3)*512+tid],   wg3=glu_w[(k+3)*512+tid+HH];
    #pragma unroll
    for(int r=0;r<4;r++){
      float4 a4=*(const float4*)&A[r][k];
      acca[r]+=a4.x*wa0+a4.y*wa1+a4.z*wa2+a4.w*wa3;
      accg[r]+=a4.x*wg0+a4.y*wg1+a4.z*wg2+a4.w*wg3;
    }
  }
  for(int r=0;r<4;r++){
    int m=m0+r;
    float hv=acca[r]*(1.0f/(1.0f+expf(-accg[r])));
    hout[m*HH+tid]=(tmask[m]!=0.0f)?0.0f:hv;
  }
}

// ---------------- depthwise conv + out proj + residual + mask ----------------
__global__ __launch_bounds__(256) void k_dwout(const float* __restrict__ hin, const float* __restrict__ resid,
    const float* __restrict__ dw, const float* __restrict__ out_w, const float* __restrict__ out_b,
    const float* __restrict__ tmask, float* __restrict__ vout){
  __shared__ float Ht[6][SS];
  __shared__ float A[4][SS];
  __shared__ float dws[3][SS];
  int m0=blockIdx.x*4, tid=threadIdx.x, b=m0>>8, s0=m0&255;
  for(int rr=0;rr<6;rr++){
    int s=s0-1+rr;
    Ht[rr][tid]=(s>=0&&s<SS)?hin[(b*SS+s)*HH+tid]:0.0f;
  }
  {
    float d0=dw[tid*3],d1=dw[tid*3+1],d2=dw[tid*3+2];
    float mx=fmaxf(d0,fmaxf(d1,d2));
    float e0=expf(d0-mx),e1=expf(d1-mx),e2=expf(d2-mx);
    float inv=1.0f/(e0+e1+e2);
    dws[0][tid]=e0*inv; dws[1][tid]=e1*inv; dws[2][tid]=e2*inv;
  }
  __syncthreads();
  for(int r=0;r<4;r++)
    A[r][tid]=dws[0][tid]*Ht[r][tid]+dws[1][tid]*Ht[r+1][tid]+dws[2][tid]*Ht[r+2][tid];
  __syncthreads();
  float acc[4]; float bn=out_b[tid];
  #pragma unroll
  for(int r=0;r<4;r++) acc[r]=bn;
  for(int k=0;k<HH;k+=4){
    float w0=out_w[(k+0)*HH+tid], w1=out_w[(k+1)*HH+tid];
    float w2=out_w[(k+2)*HH+tid], w3=out_w[(k+3)*HH+tid];
    #pragma unroll
    for(int r=0;r<4;r++){
      float4 a4=*(const float4*)&A[r][k];
      acc[r]+=a4.x*w0+a4.y*w1+a4.z*w2+a4.w*w3;
    }
  }
  for(int r=0;r<4;r++){
    int m=m0+r;
    float v=acc[r]+resid[m*HH+tid];
    vout[m*HH+tid]=(tmask[m]!=0.0f)?0.0f:v;
  }
}

// ---------------- duration head: D, alpha, cumsum, mel_len, masks ----------------
__global__ __launch_bounds__(256) void k_dur(const float* __restrict__ V2, const float* __restrict__ p1w,
    const float* __restrict__ p1b, const float* __restrict__ sdo, const float* __restrict__ rhythm,
    float* __restrict__ ws, float* __restrict__ outp){
  __shared__ float p1[HH];
  __shared__ float sd[SS];
  __shared__ float red[16];
  int b=blockIdx.x, tid=threadIdx.x;
  int wid=tid>>6, lane=tid&63;
  p1[tid]=p1w[tid];
  __syncthreads();
  float accd=p1b[0];
  const float* row=V2+(unsigned)(b*SS+tid)*HH;
  for(int k=0;k<HH;k+=4){
    float4 v=*(const float4*)&row[k];
    accd+=v.x*p1[k]+v.y*p1[k+1]+v.z*p1[k+2]+v.w*p1[k+3];
  }
  float Dv=fmaxf(accd,0.0f)+log1pf(expf(-fabsf(accd)));   // stable softplus
  if(ws[WS_TMASK+b*SS+tid]!=0.0f) Dv=0.0f;
  float sv=sdo[b*SS+tid];
  float a=Dv, c=sv;
  for(int off=32;off;off>>=1){ a+=__shfl_down(a,off); c+=__shfl_down(c,off); }
  if(lane==0){ red[wid]=a; red[wid+8]=c; }
  __syncthreads();
  float Dsum=red[0]+red[1]+red[2]+red[3];
  float pred=red[8]+red[9]+red[10]+red[11];
  float al=(pred/rhythm[b])/Dsum;
  float sDv=al*Dv;
  sd[tid]=sDv;
  __syncthreads();
  for(int off=1;off<SS;off<<=1){
    float t=(tid>=off)?sd[tid-off]:0.0f;
    __syncthreads();
    sd[tid]+=t;
    __syncthreads();
  }
  float ek=sd[tid], sk=ek-sDv;
  ws[WS_EK+b*SS+tid]=ek;
  ws[WS_SK+b*SS+tid]=sk;
  float melf=sd[SS-1];
  int mel=(int)rintf(melf); mel=mel<1?1:(mel>MLEN?MLEN:mel);
  if(tid==0){
    ws[WS_ALPHA+b]=al;
    ((int*)ws)[WS_MELI+b]=mel;
    outp[OUT_ALPHA+b]=al;
    outp[OUT_MLEN+b]=(float)mel;
  }
  for(int t=tid;t<MLEN;t+=SS) outp[OUT_MMASK+b*MLEN+t]=(t>=mel)?1.0f:0.0f;
}

// ---------------- T = conv1d(V,p2)+b ; sTt[h][s] = bf16(alpha*T) ----------------
__global__ __launch_bounds__(256) void k_T(const float* __restrict__ V2, const float* __restrict__ p2k,
    const float* __restrict__ p2b, float* __restrict__ ws){
  __shared__ float Vt[6][SS];
  int m0=blockIdx.x*4, tid=threadIdx.x, b=m0>>8, s0=m0&255;
  for(int rr=0;rr<6;rr++){
    int s=s0-1+rr;
    Vt[rr][tid]=(s>=0&&s<SS)?V2[(b*SS+s)*HH+tid]:0.0f;
  }
  __syncthreads();
  float acc[4]; float bn=p2b[tid];
  #pragma unroll
  for(int r=0;r<4;r++) acc[r]=bn;
  for(int k3=0;k3<3;k3++){
    const float* w=p2k+(unsigned)k3*HH*HH;
    for(int k=0;k<HH;k+=4){
      float w0=w[(k+0)*HH+tid], w1=w[(k+1)*HH+tid];
      float w2=w[(k+2)*HH+tid], w3=w[(k+3)*HH+tid];
      #pragma unroll
      for(int r=0;r<4;r++){
        float4 a4=*(const float4*)&Vt[r+k3][k];
        acc[r]+=a4.x*w0+a4.y*w1+a4.z*w2+a4.w*w3;
      }
    }
  }
  float al=ws[WS_ALPHA+b];
  unsigned short* stt=(unsigned short*)(ws+WS_H);
  for(int r=0;r<4;r++){
    float v=al*acc[r];
    stt[((unsigned)(b*SS+tid))*SS + (unsigned)(s0+r)]=(unsigned short)(bf16rne(v)>>16);
  }
}

// ---------------- Cv = LN16(relu(conv1d(alpha*V, cw)+cwb)) ----------------
__global__ __launch_bounds__(256) void k_cv(const float* __restrict__ V2, const float* __restrict__ cwk,
    const float* __restrict__ cwb, const float* __restrict__ cwg, const float* __restrict__ cwbe,
    float* __restrict__ ws){
  __shared__ float Vt[18][SS];
  int b=blockIdx.x>>4, tile=blockIdx.x&15, tid=threadIdx.x;
  int sbase=tile*16;
  float al=ws[WS_ALPHA+b];
  for(int rr=0;rr<18;rr++){
    int s=sbase-1+rr;
    Vt[rr][tid]=(s>=0&&s<SS)?al*V2[(b*SS+s)*HH+tid]:0.0f;
  }
  __syncthreads();
  int sl=tid>>4, oc=tid&15;
  float a0=cwb[oc],a1=0.f,a2=0.f,a3=0.f;
  for(int k3=0;k3<3;k3++){
    const float* vp=&Vt[sl+k3][0];
    const float* wpp=cwk+(unsigned)k3*HH*CWW+oc;
    for(int c=0;c<HH;c+=4){
      a0+=vp[c+0]*wpp[(c+0)*CWW];
      a1+=vp[c+1]*wpp[(c+1)*CWW];
      a2+=vp[c+2]*wpp[(c+2)*CWW];
      a3+=vp[c+3]*wpp[(c+3)*CWW];
    }
  }
  float acc=fmaxf((a0+a1)+(a2+a3),0.0f);
  float ssum=acc, qsum=acc*acc;
  for(int off=8;off;off>>=1){ ssum+=__shfl_xor(ssum,off); qsum+=__shfl_xor(qsum,off); }
  float mean=ssum*(1.0f/CWW), var=qsum*(1.0f/CWW)-mean*mean;
  float cv=(acc-mean)*rsqrtf(var+1e-5f)*cwg[oc]+cwbe[oc];
  ws[WS_CV+(unsigned)(b*SS+sbase+sl)*CWW+oc]=cv;
}

// ---------------- CP + affine fast-path tables (CCv/SSv/CCi/SSi) ----------------
__global__ __launch_bounds__(256) void k_cp(const float* __restrict__ mkb1k, const float* __restrict__ mkb1b,
    float* __restrict__ ws){
  __shared__ float CvL[258][17];
  __shared__ float k1c[3][3][CWW][NOC];
  __shared__ float kab[3][3][2][NOC];
  __shared__ float skE[258], ekE[258], fiE[258];
  int b=blockIdx.x, tid=threadIdx.x;
  for(int i=tid;i<3*3*CWW*NOC;i+=256){
    int oc=i&15, ic=(i>>4)&15, kk=i>>8;
    int kw=kk%3, kh=kk/3;
    k1c[kh][kw][ic][oc]=mkb1k[((kh*3+kw)*18+2+ic)*NOC+oc];
  }
  for(int i=tid;i<3*3*2*NOC;i+=256){
    int oc=i&15, ch=(i>>4)&1, kk=i>>5;
    int kw=kk%3, kh=kk/3;
    kab[kh][kw][ch][oc]=mkb1k[((kh*3+kw)*18+ch)*NOC+oc];
  }
  for(int i=tid;i<SS*CWW;i+=256) CvL[1+(i>>4)][i&15]=ws[WS_CV+(unsigned)b*SS*CWW+i];
  if(tid<CWW){ CvL[0][tid]=0.f; CvL[257][tid]=0.f; }
  if(tid<258){
    float sk=0.f, ek=0.f, fi=0.f;
    if(tid>=1 && tid<=SS){
      sk=ws[WS_SK+b*SS+tid-1];
      ek=ws[WS_EK+b*SS+tid-1];
      fi=(ws[WS_TMASK+b*SS+tid-1]!=0.0f)?0.0f:1.0f;
    }
    skE[tid]=sk; ekE[tid]=ek; fiE[tid]=fi;
  }
  __syncthreads();
  float* cpg=ws+WS_CP+(unsigned)b*3*SS*NOC;
  float ccv[16],ssv[16],cci[16],ssi[16];
  #pragma unroll
  for(int oc=0;oc<NOC;oc++){ float bb=mkb1b[oc]; ccv[oc]=bb; cci[oc]=bb; ssv[oc]=0.f; ssi[oc]=0.f; }
  for(int dt=0;dt<3;dt++){
    float acc[NOC];
    #pragma unroll
    for(int oc=0;oc<NOC;oc++) acc[oc]=0.f;
    #pragma unroll
    for(int ds=0;ds<3;ds++){
      #pragma unroll
      for(int ic=0;ic<CWW;ic++){
        float v=CvL[tid+ds][ic];
        #pragma unroll
        for(int oc=0;oc<NOC;oc++) acc[oc]+=v*k1c[dt][ds][ic][oc];
      }
    }
    for(int oc=0;oc<NOC;oc++) cpg[(unsigned)(dt*SS+tid)*NOC+oc]=acc[oc];
    float va[16],vb[16],ia[16],ib2[16];
    #pragma unroll
    for(int oc=0;oc<NOC;oc++){ va[oc]=0.f; vb[oc]=0.f; ia[oc]=0.f; ib2[oc]=0.f; }
    #pragma unroll
    for(int ds=0;ds<3;ds++){
      int j=tid+ds;
      float inb=(j>=1&&j<=SS)?1.0f:0.0f;
      float fb=fiE[j];
      float skv=skE[j], ekv=ekE[j];
      #pragma unroll
      for(int oc=0;oc<NOC;oc++){
        float ka=kab[dt][ds][0][oc], kb=kab[dt][ds][1][oc];
        float d=ka-kb, e=kb*ekv-ka*skv;
        va[oc]+=inb*d; vb[oc]+=inb*e; ia[oc]+=fb*d; ib2[oc]+=fb*e;
      }
    }
    float dtf=(float)dt;
    #pragma unroll
    for(int oc=0;oc<NOC;oc++){
      ccv[oc]+=acc[oc]+vb[oc]+dtf*va[oc]; ssv[oc]+=va[oc];
      cci[oc]+=acc[oc]+ib2[oc]+dtf*ia[oc]; ssi[oc]+=ia[oc];
    }
  }
  unsigned base=(unsigned)(b*SS+tid)*16u;
  for(int oc=0;oc<NOC;oc++){
    ws[WS_CCV+base+oc]=ccv[oc];
    ws[WS_SSV+base+oc]=ssv[oc];
    ws[WS_CCI+base+oc]=cci[oc];
    ws[WS_SSI+base+oc]=ssi[oc];
  }
}

// ---------------- stage B ----------------
__global__ __launch_bounds__(256,2) void k_stageB(
    const float* __restrict__ ws, const float* __restrict__ mkb1k, const float* __restrict__ mkb1b,
    const float* __restrict__ mkb2k, const float* __restrict__ mkb2b,
    const float* __restrict__ lww, const float* __restrict__ lwb,
    const float* __restrict__ lng, const float* __restrict__ lnb,
    float* __restrict__ outp){
  __shared__ short ringh[3][258][RB];
  __shared__ float skL[258], ekL[258], finL[258];
  __shared__ __align__(16) unsigned short Wb[16][264];   // bf16 W rows (8-15 zero)
  __shared__ float UpL[8][264];
  __shared__ float wscL[SS];
  __shared__ float red[16];
  __shared__ float mrs[8][2];
  int bx=blockIdx.x, b=bx/125, chunk=bx%125, t0=chunk*8, tid=threadIdx.x;
  int wid=tid>>6, lane=tid&63;
  int lq=lane>>4, lm=lane&15;
  if(tid<258){
    float sk=0.f, ek=0.f, fin=0.f;
    if(tid>=1 && tid<=SS){
      sk=ws[WS_SK+b*SS+tid-1];
      ek=ws[WS_EK+b*SS+tid-1];
      fin=(ws[WS_TMASK+b*SS+tid-1]!=0.0f)?0.0f:1.0f;
    }
    skL[tid]=sk; ekL[tid]=ek; finL[tid]=fin;
  }
  if(tid<72){
    int sl=tid/24, rem=tid%24;
    int row=(rem<12)?0:257, c=(rem%12)*2;
    *(int*)&ringh[sl][row][c]=0;
  }
  for(int i=tid;i<16*264/2;i+=256) ((int*)&Wb[0][0])[i]=0;
  int mel=((const int*)ws)[WS_MELI+b];
  __syncthreads();

  const float* cpb=ws+WS_CP+(unsigned)b*3*SS*NOC;

  // per-lane MFMA constants for conv2 (same as R2)
  unsigned offA[5]; int dtL[5], zgL[5];
  bfrag bfw[5];
  {
    #pragma unroll
    for(int i=0;i<5;i++){
      int g=4*i+lq;
      int dt,ds,hf,zg;
      if(g<18){ dt=g/6; int rm=g-6*dt; ds=rm>>1; hf=rm&1; zg=0; }
      else { dt=0; ds=0; hf=0; zg=1; }
      int srow=wid*64+lm+ds;
      offA[i]=(unsigned)((srow*RB+8*hf)*2);
      dtL[i]=dt; zgL[i]=zg;
      int pk[4];
      if(!zg){
        #pragma unroll
        for(int j=0;j<4;j++){
          unsigned u0=bf16rne(mkb2k[(8*g+2*j)*NOC+lm]);
          unsigned u1=bf16rne(mkb2k[(8*g+2*j+1)*NOC+lm]);
          pk[j]=(int)((u0>>16)|(u1&0xffff0000u));
        }
      } else pk[0]=pk[1]=pk[2]=pk[3]=0;
      bfw[i]=__builtin_bit_cast(bfrag, make_int4(pk[0],pk[1],pk[2],pk[3]));
    }
  }
  float b2v=mkb2b[lm];
  float lwwv=lww[lm];
  float lwb0=lwb[0];
  const char* ringB=(const char*)&ringh[0][0][0];
  bfrag azero={};

  auto conv1row=[&](int T){
    int s=tid;
    float acc[NOC];
    bool fv=(T>=1)&&(T<=998)&&(T+1<mel);
    bool fi=(T>=2)&&(T<=998)&&(T-1>=mel);
    if(fv||fi){
      const float* cc=ws+(fv?WS_CCV:WS_CCI)+(unsigned)(b*SS+s)*16u;
      const float* s2=ws+(fv?WS_SSV:WS_SSI)+(unsigned)(b*SS+s)*16u;
      float Tf=(float)T;
      #pragma unroll
      for(int q=0;q<4;q++){
        float4 c4=((const float4*)cc)[q];
        float4 s4=((const float4*)s2)[q];
        acc[4*q+0]=c4.x+Tf*s4.x; acc[4*q+1]=c4.y+Tf*s4.y;
        acc[4*q+2]=c4.z+Tf*s4.z; acc[4*q+3]=c4.w+Tf*s4.w;
      }
    } else {
      #pragma unroll
      for(int oc=0;oc<NOC;oc++) acc[oc]=mkb1b[oc];
      #pragma unroll
      for(int dt=0;dt<3;dt++){
        int tr=T+dt-1;
        if(tr<0||tr>=MLEN) continue;
        bool valid=(tr<mel);
        float tt=(float)(tr+1);
        float gg[3], hh[3];
        #pragma unroll
        for(int ds=0;ds<3;ds++){
          int j=s+ds;
          float f = valid ? ((j>=1&&j<=SS)?1.0f:0.0f) : finL[j];
          gg[ds]=f*(tt-skL[j]);
          hh[ds]=f*(ekL[j]-tt);
        }
        const float* cpr=cpb+(unsigned)(dt*SS+s)*NOC;
        float4 c0=((const float4*)cpr)[0], c1=((const float4*)cpr)[1];
        float4 c2=((const float4*)cpr)[2], c3=((const float4*)cpr)[3];
        acc[0]+=c0.x; acc[1]+=c0.y; acc[2]+=c0.z; acc[3]+=c0.w;
        acc[4]+=c1.x; acc[5]+=c1.y; acc[6]+=c1.z; acc[7]+=c1.w;
        acc[8]+=c2.x; acc[9]+=c2.y; acc[10]+=c2.z; acc[11]+=c2.w;
        acc[12]+=c3.x; acc[13]+=c3.y; acc[14]+=c3.z; acc[15]+=c3.w;
        #pragma unroll
        for(int ds=0;ds<3;ds++){
          const float* kA=mkb1k+((dt*3+ds)*18+0)*NOC;
          const float* kB=mkb1k+((dt*3+ds)*18+1)*NOC;
          #pragma unroll
          for(int oc=0;oc<NOC;oc++) acc[oc]+=gg[ds]*kA[oc]+hh[ds]*kB[oc];
        }
      }
    }
    int slot=T%3;
    int pk[8];
    #pragma unroll
    for(int j=0;j<8;j++){
      float x0=acc[2*j], x1=acc[2*j+1];
      float s0=x0/(1.0f+__expf(-x0));
      float s1=x1/(1.0f+__expf(-x1));
      unsigned u0=bf16rne(s0), u1=bf16rne(s1);
      pk[j]=(int)((u0>>16)|(u1&0xffff0000u));
    }
    int4* dst=(int4*)&ringh[slot][s+1][0];
    dst[0]=make_int4(pk[0],pk[1],pk[2],pk[3]);
    dst[1]=make_int4(pk[4],pk[5],pk[6],pk[7]);
  };

  if(t0>0) conv1row(t0-1);
  conv1row(t0);

  #pragma unroll 1
  for(int r=0;r<8;r++){
    int t=t0+r;
    if(t+1<MLEN) conv1row(t+1);
    __syncthreads();
    int tmod=t%3;
    ffrag acc2[4];
    #pragma unroll
    for(int tt=0;tt<4;tt++){ acc2[tt][0]=b2v; acc2[tt][1]=b2v; acc2[tt][2]=b2v; acc2[tt][3]=b2v; }
    #pragma unroll
    for(int i=0;i<5;i++){
      int dt=dtL[i];
      int x=tmod+dt+2; x=(x>=3)?x-3:x; x=(x>=3)?x-3:x;
      int tr=t+dt-1;
      bool av=((unsigned)tr<(unsigned)MLEN)&&(!zgL[i]);
      const char* rp=ringB+(unsigned)x*(258u*RB*2u)+offA[i];
      #pragma unroll
      for(int tt=0;tt<4;tt++){
        int4 ra=*(const int4*)(rp+tt*(16*RB*2));
        bfrag a=av?__builtin_bit_cast(bfrag,ra):azero;
        acc2[tt]=__builtin_amdgcn_mfma_f32_16x16x32_bf16(a,bfw[i],acc2[tt],0,0,0);
      }
    }
    #pragma unroll
    for(int tt=0;tt<4;tt++){
      float out4[4];
      #pragma unroll
      for(int q=0;q<4;q++){
        float xx=acc2[tt][q];
        float pv=(xx/(1.0f+__expf(-xx)))*lwwv;
        pv+=__shfl_xor(pv,1); pv+=__shfl_xor(pv,2); pv+=__shfl_xor(pv,4); pv+=__shfl_xor(pv,8);
        out4[q]=pv+lwb0;
      }
      if(lm==0){
        *(float4*)&wscL[wid*64+tt*16+lq*4]=make_float4(out4[0],out4[1],out4[2],out4[3]);
      }
    }
    __syncthreads();
    float fm=finL[tid+1];
    float wsc=wscL[tid];
    float val=(fm!=0.0f)?wsc:-3.0e38f;
    float mx=val;
    for(int off=32;off;off>>=1) mx=fmaxf(mx,__shfl_down(mx,off));
    if(lane==0) red[wid]=mx;
    __syncthreads();
    mx=fmaxf(fmaxf(red[0],red[1]),fmaxf(red[2],red[3]));
    float e=(fm!=0.0f)?__expf(wsc-mx):0.0f;
    float sm=e;
    for(int off=32;off;off>>=1) sm+=__shfl_down(sm,off);
    if(lane==0) red[8+wid]=sm;
    __syncthreads();
    sm=red[8]+red[9]+red[10]+red[11];
    float wv=e/sm;
    Wb[r][tid]=(unsigned short)(bf16rne(wv)>>16);
    outp[OUT_W+(unsigned)(b*MLEN+t)*SS+tid]=wv;
    __syncthreads();
  }

  // ---- up = W @ sT via MFMA (M=8 in 16, N=256, K=256) ----
  const unsigned short* sttb=(const unsigned short*)(ws+WS_H)+(unsigned)b*65536u;
  ffrag uacc[4];
  #pragma unroll
  for(int tt=0;tt<4;tt++){ uacc[tt][0]=0.f; uacc[tt][1]=0.f; uacc[tt][2]=0.f; uacc[tt][3]=0.f; }
  int hbase=wid*64+lm;
  #pragma unroll
  for(int k0=0;k0<8;k0++){
    int kk=k0*32+lq*8;
    bfrag af=__builtin_bit_cast(bfrag, *(const int4*)&Wb[lm][kk]);
    #pragma unroll
    for(int tt=0;tt<4;tt++){
      int h=hbase+tt*16;
      int4 rb=*(const int4*)(sttb+(unsigned)h*256u+(unsigned)kk);
      uacc[tt]=__builtin_amdgcn_mfma_f32_16x16x32_bf16(af,__builtin_bit_cast(bfrag,rb),uacc[tt],0,0,0);
    }
  }
  #pragma unroll
  for(int tt=0;tt<4;tt++){
    #pragma unroll
    for(int reg=0;reg<4;reg++){
      int row=lq*4+reg;
      if(row<8) UpL[row][hbase+tt*16]=uacc[tt][reg];
    }
  }
  __syncthreads();
  for(int rr=0;rr<2;rr++){
    int r=wid*2+rr;
    float x0=UpL[r][lane],x1=UpL[r][lane+64],x2=UpL[r][lane+128],x3=UpL[r][lane+192];
    float s1=x0+x1+x2+x3, q1=x0*x0+x1*x1+x2*x2+x3*x3;
    for(int off=32;off;off>>=1){ s1+=__shfl_down(s1,off); q1+=__shfl_down(q1,off); }
    if(lane==0){
      float mean=s1*(1.0f/HH);
      float var=q1*(1.0f/HH)-mean*mean;
      mrs[r][0]=mean; mrs[r][1]=rsqrtf(var+1e-5f);
    }
  }
  __syncthreads();
  float gg=lng[tid], bb=lnb[tid];
  #pragma unroll
  for(int r=0;r<8;r++){
    int t=t0+r;
    float v=(t<mel)?((UpL[r][tid]-mrs[r][0])*mrs[r][1]*gg+bb):0.0f;
    outp[OUT_UP+(unsigned)(b*MLEN+t)*SS+tid]=v;
  }
}

extern "C" void kernel_launch(void* const* d_in, const int* in_sizes, int n_in,
                              void* d_out, int out_size, void* d_ws, size_t ws_size,
                              hipStream_t stream){
  const float* ce   =(const float*)d_in[0];
  const float* spk  =(const float*)d_in[1];
  const float* rhy  =(const float*)d_in[2];
  const float* sdo  =(const float*)d_in[3];
  const void*  tmr  =d_in[4];
  const float* in_w =(const float*)d_in[5];
  const float* in_b =(const float*)d_in[6];
  const float* l0lg =(const float*)d_in[7];
  const float* l0lb =(const float*)d_in[8];
  const float* l0gw =(const float*)d_in[9];
  const float* l0gb =(const float*)d_in[10];
  const float* l0dw =(const float*)d_in[11];
  const float* l0ow =(const float*)d_in[12];
  const float* l0ob =(const float*)d_in[13];
  const float* l1lg =(const float*)d_in[14];
  const float* l1lb =(const float*)d_in[15];
  const float* l1gw =(const float*)d_in[16];
  const float* l1gb =(const float*)d_in[17];
  const float* l1dw =(const float*)d_in[18];
  const float* l1ow =(const float*)d_in[19];
  const float* l1ob =(const float*)d_in[20];
  const float* p1w  =(const float*)d_in[21];
  const float* p1b  =(const float*)d_in[22];
  const float* p2k  =(const float*)d_in[23];
  const float* p2b  =(const float*)d_in[24];
  const float* cwk  =(const float*)d_in[25];
  const float* cwb  =(const float*)d_in[26];
  const float* cwg  =(const float*)d_in[27];
  const float* cwbe =(const float*)d_in[28];
  const float* m1k  =(const float*)d_in[29];
  const float* m1b  =(const float*)d_in[30];
  const float* m2k  =(const float*)d_in[31];
  const float* m2b  =(const float*)d_in[32];
  const float* lww  =(const float*)d_in[33];
  const float* lwbp =(const float*)d_in[34];
  const float* lng  =(const float*)d_in[35];
  const float* lnb  =(const float*)d_in[36];
  float* ws=(float*)d_ws;
  float* outp=(float*)d_out;

  k_mask  <<<1,256,0,stream>>>(tmr, ws);
  k_inproj<<<512,256,0,stream>>>(ce, spk, in_w, in_b, ws);
  k_glu   <<<512,256,0,stream>>>(ws+WS_X,  l0gw, l0gb, l0lg, l0lb, ws+WS_TMASK, ws+WS_H);
  k_dwout <<<512,256,0,stream>>>(ws+WS_H,  ws+WS_X,  l0dw, l0ow, l0ob, ws+WS_TMASK, ws+WS_V1);
  k_glu   <<<512,256,0,stream>>>(ws+WS_V1, l1gw, l1gb, l1lg, l1lb, ws+WS_TMASK, ws+WS_H);
  k_dwout <<<512,256,0,stream>>>(ws+WS_H,  ws+WS_V1, l1dw, l1ow, l1ob, ws+WS_TMASK, ws+WS_V2);
  k_dur   <<<8,256,0,stream>>>(ws+WS_V2, p1w, p1b, sdo, rhy, ws, outp);
  k_T     <<<512,256,0,stream>>>(ws+WS_V2, p2k, p2b, ws);
  k_cv    <<<128,256,0,stream>>>(ws+WS_V2, cwk, cwb, cwg, cwbe, ws);
  k_cp    <<<8,256,0,stream>>>(m1k, m1b, ws);
  k_stageB<<<1000,256,0,stream>>>(ws, m1k, m1b, m2k, m2b, lww, lwbp, lng, lnb, outp);
}

// Round 4
// 328.177 us; speedup vs baseline: 1.8121x; 1.3686x over previous
//
#include <hip/hip_runtime.h>
#include <math.h>

#define SS 256
#define HH 256
#define MLEN 1000
#define CWW 16
#define NOC 16
#define RB 24          // ring row stride in bf16 elems (48B, 16B-aligned)

typedef __attribute__((ext_vector_type(8))) short bfrag;
typedef __attribute__((ext_vector_type(4))) float ffrag;

// float-indexed workspace offsets (total 2,693,136 floats = 10.77 MB; R1 proved >=11.03 MB exists)
#define WS_X      0u          // [2048][256] fp32
#define WS_V1     524288u
#define WS_V2     1048576u
#define WS_HB     1572864u    // h bf16 [2048][256] (262144 floats)
#define WS_STT    1835008u    // sTt bf16 [8][256 h][256 s] (262144 floats)
#define WS_WB     2097152u    // packed bf16 weights (327680 floats)
#define WS_CCV    2424832u    // [8][256][16]
#define WS_SSV    2457600u
#define WS_CCI    2490368u
#define WS_SSI    2523136u
#define WS_CP     2555904u    // [8][3][256][16]
#define WS_CV     2654208u    // [8][256][16]
#define WS_EK     2686976u
#define WS_SK     2689024u
#define WS_ALPHA  2691072u
#define WS_MELI   2691080u
#define WS_TMASK  2691088u

// packed-weight offsets in shorts relative to (unsigned short*)(ws+WS_WB)
#define PK_IN     0u
#define PK_GLU0   65536u
#define PK_GLU1   196608u
#define PK_OUT0   327680u
#define PK_OUT1   393216u
#define PK_P2     458752u

// output offsets
#define OUT_UP    0u
#define OUT_W     2048000u
#define OUT_ALPHA 4096000u
#define OUT_MLEN  4096008u
#define OUT_MMASK 4096016u

__device__ __forceinline__ unsigned bf16rne(float x){
  unsigned u=__float_as_uint(x);
  u += 0x7fffu + ((u>>16)&1u);
  return u;
}
__device__ __forceinline__ unsigned short bf16h(float x){ return (unsigned short)(bf16rne(x)>>16); }
__device__ __forceinline__ float bf2f(unsigned short u){ return __uint_as_float(((unsigned)u)<<16); }
// fragment index: B[k][n] for K x N matrix, KT=K/32
__device__ __forceinline__ unsigned frag_idx(int k,int n,int KT){
  return (unsigned)(((((n>>4)*KT+(k>>5))*64 + ((k>>3)&3)*16 + (n&15))<<3) + (k&7));
}

// ---------------- text_mask canonicalization ----------------
__global__ __launch_bounds__(256) void k_mask(const void* __restrict__ traw, float* __restrict__ ws){
  __shared__ int s_fu, s_ff, s_nz;
  const unsigned char* mb=(const unsigned char*)traw;
  const unsigned int*  mw=(const unsigned int*)traw;
  int tid=threadIdx.x;
  if(tid==0){s_fu=0;s_ff=0;s_nz=0;}
  __syncthreads();
  int fu=0,ff=0,nz=0;
  for(int w=tid;w<512;w+=256){
    unsigned int v=mw[w];
    if(v){ nz=1; if(v==0x3F800000u) ff=1; else if(v&0xFFFFFF00u) fu=1; }
  }
  if(fu) atomicOr(&s_fu,1);
  if(ff) atomicOr(&s_ff,1);
  if(nz) atomicOr(&s_nz,1);
  __syncthreads();
  int words = (s_ff || (!s_fu && s_nz));
  for(int i=tid;i<2048;i+=256){
    unsigned int v = words ? mw[i] : (unsigned int)mb[i];
    ws[WS_TMASK+i] = v ? 1.0f : 0.0f;
  }
}

// ---------------- pack all front-end weights to bf16 MFMA-fragment layout ----------------
__global__ __launch_bounds__(256) void k_prep(const float* __restrict__ in_w,
    const float* __restrict__ g0, const float* __restrict__ g1,
    const float* __restrict__ o0, const float* __restrict__ o1,
    const float* __restrict__ p2k, float* __restrict__ ws){
  unsigned short* wb=(unsigned short*)(ws+WS_WB);
  int gid=blockIdx.x*256+threadIdx.x, stride=gridDim.x*256;
  for(int i=gid;i<65536;i+=stride){ int k=i>>8,n=i&255; wb[PK_IN  +frag_idx(k,n,8)]=bf16h(in_w[i]); }
  for(int i=gid;i<131072;i+=stride){ int k=i>>9,n=i&511; wb[PK_GLU0+frag_idx(k,n,8)]=bf16h(g0[i]); }
  for(int i=gid;i<131072;i+=stride){ int k=i>>9,n=i&511; wb[PK_GLU1+frag_idx(k,n,8)]=bf16h(g1[i]); }
  for(int i=gid;i<65536;i+=stride){ int k=i>>8,n=i&255; wb[PK_OUT0+frag_idx(k,n,8)]=bf16h(o0[i]); }
  for(int i=gid;i<65536;i+=stride){ int k=i>>8,n=i&255; wb[PK_OUT1+frag_idx(k,n,8)]=bf16h(o1[i]); }
  for(int i=gid;i<196608;i+=stride){ int k3=i>>16,r=i&65535,k=r>>8,n=r&255;
    wb[PK_P2+(unsigned)k3*65536u+frag_idx(k,n,8)]=bf16h(p2k[i]); }
}

// ---------------- input projection (MFMA): x = concat(ce,spk) @ in_w + b ----------------
__global__ __launch_bounds__(256) void k_inproj2(const float* __restrict__ ce, const float* __restrict__ spk,
    const unsigned short* __restrict__ wb, const float* __restrict__ in_b, float* __restrict__ ws){
  __shared__ unsigned short Abf[16][264];
  int m0=(blockIdx.x>>1)*16, nh=blockIdx.x&1, tid=threadIdx.x, b=m0>>8;
  for(int it=0;it<16;it++){
    int m=m0+it;
    float v=(tid<192)? ce[m*192+tid] : spk[b*64+tid-192];
    Abf[it][tid]=bf16h(v);
  }
  __syncthreads();
  int w=tid>>6, lane=tid&63, lq=lane>>4, lm=lane&15;
  ffrag acc[2];
  #pragma unroll
  for(int tt=0;tt<2;tt++){ acc[tt][0]=0.f;acc[tt][1]=0.f;acc[tt][2]=0.f;acc[tt][3]=0.f; }
  #pragma unroll
  for(int kt=0;kt<8;kt++){
    bfrag af=*(const bfrag*)&Abf[lm][kt*32+lq*8];
    #pragma unroll
    for(int tt=0;tt<2;tt++){
      int nt=nh*8+w*2+tt;
      bfrag bf=*(const bfrag*)(wb+((((unsigned)(nt*8+kt))*64u+(unsigned)lane)<<3));
      acc[tt]=__builtin_amdgcn_mfma_f32_16x16x32_bf16(af,bf,acc[tt],0,0,0);
    }
  }
  #pragma unroll
  for(int tt=0;tt<2;tt++){
    int n=nh*128+w*32+tt*16+lm;
    float bn=in_b[n];
    #pragma unroll
    for(int reg=0;reg<4;reg++)
      ws[WS_X+(unsigned)(m0+lq*4+reg)*256u+n]=acc[tt][reg]+bn;
  }
}

// ---------------- LN + GLU (MFMA): h = a*sigmoid(g), masked, bf16 out ----------------
__global__ __launch_bounds__(256) void k_glu2(const float* __restrict__ xin,
    const unsigned short* __restrict__ wb, const float* __restrict__ glu_b,
    const float* __restrict__ lgam, const float* __restrict__ lbet,
    const float* __restrict__ tmask, unsigned short* __restrict__ hout){
  __shared__ float Xf[16][264];
  __shared__ unsigned short Abf[16][264];
  __shared__ float gb[2][256];
  __shared__ float tmL[16];
  int m0=(blockIdx.x>>1)*16, nh=blockIdx.x&1, tid=threadIdx.x;
  gb[0][tid]=lgam[tid]; gb[1][tid]=lbet[tid];
  if(tid<16) tmL[tid]=tmask[m0+tid];
  for(int it=0;it<16;it++) Xf[it][tid]=xin[(unsigned)(m0+it)*256u+tid];
  __syncthreads();
  int r=tid>>4, seg=tid&15;
  float s=0.f,q=0.f;
  #pragma unroll
  for(int j4=0;j4<4;j4++){
    float4 v=*(const float4*)&Xf[r][seg*16+j4*4];
    s+=v.x+v.y+v.z+v.w; q+=v.x*v.x+v.y*v.y+v.z*v.z+v.w*v.w;
  }
  s+=__shfl_xor(s,1); q+=__shfl_xor(q,1);
  s+=__shfl_xor(s,2); q+=__shfl_xor(q,2);
  s+=__shfl_xor(s,4); q+=__shfl_xor(q,4);
  s+=__shfl_xor(s,8); q+=__shfl_xor(q,8);
  float mean=s*(1.0f/256.0f), rstd=rsqrtf(q*(1.0f/256.0f)-mean*mean+1e-5f);
  #pragma unroll
  for(int j4=0;j4<4;j4++){
    int c=seg*16+j4*4;
    float4 v=*(const float4*)&Xf[r][c];
    unsigned short o0=bf16h((v.x-mean)*rstd*gb[0][c+0]+gb[1][c+0]);
    unsigned short o1=bf16h((v.y-mean)*rstd*gb[0][c+1]+gb[1][c+1]);
    unsigned short o2=bf16h((v.z-mean)*rstd*gb[0][c+2]+gb[1][c+2]);
    unsigned short o3=bf16h((v.w-mean)*rstd*gb[0][c+3]+gb[1][c+3]);
    *(uint2*)&Abf[r][c]=make_uint2((unsigned)o0|((unsigned)o1<<16),(unsigned)o2|((unsigned)o3<<16));
  }
  __syncthreads();
  int w=tid>>6, lane=tid&63, lq=lane>>4, lm=lane&15;
  ffrag aca[2], acg[2];
  #pragma unroll
  for(int tt=0;tt<2;tt++){ aca[tt][0]=0;aca[tt][1]=0;aca[tt][2]=0;aca[tt][3]=0;
                           acg[tt][0]=0;acg[tt][1]=0;acg[tt][2]=0;acg[tt][3]=0; }
  #pragma unroll
  for(int kt=0;kt<8;kt++){
    bfrag af=*(const bfrag*)&Abf[lm][kt*32+lq*8];
    #pragma unroll
    for(int tt=0;tt<2;tt++){
      int nta=nh*8+w*2+tt, ntg=nta+16;
      bfrag bfa=*(const bfrag*)(wb+((((unsigned)(nta*8+kt))*64u+(unsigned)lane)<<3));
      bfrag bfg=*(const bfrag*)(wb+((((unsigned)(ntg*8+kt))*64u+(unsigned)lane)<<3));
      aca[tt]=__builtin_amdgcn_mfma_f32_16x16x32_bf16(af,bfa,aca[tt],0,0,0);
      acg[tt]=__builtin_amdgcn_mfma_f32_16x16x32_bf16(af,bfg,acg[tt],0,0,0);
    }
  }
  #pragma unroll
  for(int tt=0;tt<2;tt++){
    int n=nh*128+w*32+tt*16+lm;
    float ba=glu_b[n], bg=glu_b[n+256];
    #pragma unroll
    for(int reg=0;reg<4;reg++){
      int row=lq*4+reg;
      float a=aca[tt][reg]+ba, g=acg[tt][reg]+bg;
      float hv=a*(1.0f/(1.0f+__expf(-g)));
      if(tmL[row]!=0.0f) hv=0.0f;
      hout[(unsigned)(m0+row)*256u+n]=bf16h(hv);
    }
  }
}

// ---------------- dwconv + out-proj (MFMA) + residual + mask ----------------
__global__ __launch_bounds__(256) void k_dwout2(const unsigned short* __restrict__ hb,
    const float* __restrict__ resid, const unsigned short* __restrict__ wb,
    const float* __restrict__ dw, const float* __restrict__ out_b,
    const float* __restrict__ tmask, float* __restrict__ vout){
  __shared__ unsigned short Hb[18][264];
  __shared__ unsigned short Abf[16][264];
  __shared__ float dws[3][256];
  __shared__ float tmL[16];
  int m0=(blockIdx.x>>1)*16, nh=blockIdx.x&1, tid=threadIdx.x, b=m0>>8, s0=m0&255;
  for(int it=0;it<18;it++){
    int sI=s0-1+it;
    Hb[it][tid]=(sI>=0&&sI<256)? hb[(unsigned)(b*256+sI)*256u+tid] : (unsigned short)0;
  }
  {
    float d0=dw[tid*3],d1=dw[tid*3+1],d2=dw[tid*3+2];
    float mx=fmaxf(d0,fmaxf(d1,d2));
    float e0=expf(d0-mx),e1=expf(d1-mx),e2=expf(d2-mx);
    float inv=1.0f/(e0+e1+e2);
    dws[0][tid]=e0*inv; dws[1][tid]=e1*inv; dws[2][tid]=e2*inv;
  }
  if(tid<16) tmL[tid]=tmask[m0+tid];
  __syncthreads();
  float w0=dws[0][tid],w1=dws[1][tid],w2=dws[2][tid];
  for(int it=0;it<16;it++){
    float a=w0*bf2f(Hb[it][tid])+w1*bf2f(Hb[it+1][tid])+w2*bf2f(Hb[it+2][tid]);
    Abf[it][tid]=bf16h(a);
  }
  __syncthreads();
  int w=tid>>6, lane=tid&63, lq=lane>>4, lm=lane&15;
  ffrag acc[2];
  #pragma unroll
  for(int tt=0;tt<2;tt++){ acc[tt][0]=0;acc[tt][1]=0;acc[tt][2]=0;acc[tt][3]=0; }
  #pragma unroll
  for(int kt=0;kt<8;kt++){
    bfrag af=*(const bfrag*)&Abf[lm][kt*32+lq*8];
    #pragma unroll
    for(int tt=0;tt<2;tt++){
      int nt=nh*8+w*2+tt;
      bfrag bf=*(const bfrag*)(wb+((((unsigned)(nt*8+kt))*64u+(unsigned)lane)<<3));
      acc[tt]=__builtin_amdgcn_mfma_f32_16x16x32_bf16(af,bf,acc[tt],0,0,0);
    }
  }
  #pragma unroll
  for(int tt=0;tt<2;tt++){
    int n=nh*128+w*32+tt*16+lm;
    float bn=out_b[n];
    #pragma unroll
    for(int reg=0;reg<4;reg++){
      int row=lq*4+reg, m=m0+row;
      float v=acc[tt][reg]+bn+resid[(unsigned)m*256u+n];
      vout[(unsigned)m*256u+n]=(tmL[row]!=0.0f)?0.0f:v;
    }
  }
}

// ---------------- duration head (fp32, exact) ----------------
__global__ __launch_bounds__(256) void k_dur(const float* __restrict__ V2, const float* __restrict__ p1w,
    const float* __restrict__ p1b, const float* __restrict__ sdo, const float* __restrict__ rhythm,
    float* __restrict__ ws, float* __restrict__ outp){
  __shared__ float p1[HH];
  __shared__ float sd[SS];
  __shared__ float red[16];
  int b=blockIdx.x, tid=threadIdx.x;
  int wid=tid>>6, lane=tid&63;
  p1[tid]=p1w[tid];
  __syncthreads();
  float accd=p1b[0];
  const float* row=V2+(unsigned)(b*SS+tid)*HH;
  for(int k=0;k<HH;k+=4){
    float4 v=*(const float4*)&row[k];
    accd+=v.x*p1[k]+v.y*p1[k+1]+v.z*p1[k+2]+v.w*p1[k+3];
  }
  float Dv=fmaxf(accd,0.0f)+log1pf(expf(-fabsf(accd)));
  if(ws[WS_TMASK+b*SS+tid]!=0.0f) Dv=0.0f;
  float sv=sdo[b*SS+tid];
  float a=Dv, c=sv;
  for(int off=32;off;off>>=1){ a+=__shfl_down(a,off); c+=__shfl_down(c,off); }
  if(lane==0){ red[wid]=a; red[wid+8]=c; }
  __syncthreads();
  float Dsum=red[0]+red[1]+red[2]+red[3];
  float pred=red[8]+red[9]+red[10]+red[11];
  float al=(pred/rhythm[b])/Dsum;
  float sDv=al*Dv;
  sd[tid]=sDv;
  __syncthreads();
  for(int off=1;off<SS;off<<=1){
    float t=(tid>=off)?sd[tid-off]:0.0f;
    __syncthreads();
    sd[tid]+=t;
    __syncthreads();
  }
  float ek=sd[tid], sk=ek-sDv;
  ws[WS_EK+b*SS+tid]=ek;
  ws[WS_SK+b*SS+tid]=sk;
  float melf=sd[SS-1];
  int mel=(int)rintf(melf); mel=mel<1?1:(mel>MLEN?MLEN:mel);
  if(tid==0){
    ws[WS_ALPHA+b]=al;
    ((int*)ws)[WS_MELI+b]=mel;
    outp[OUT_ALPHA+b]=al;
    outp[OUT_MLEN+b]=(float)mel;
  }
  for(int t=tid;t<MLEN;t+=SS) outp[OUT_MMASK+b*MLEN+t]=(t>=mel)?1.0f:0.0f;
}

// ---------------- T conv (MFMA): sTt[h][s] = bf16(alpha*(conv1d(V2,p2)+b)) ----------------
__global__ __launch_bounds__(256) void k_T2(const float* __restrict__ V2,
    const unsigned short* __restrict__ wb, const float* __restrict__ p2b, float* __restrict__ ws){
  __shared__ unsigned short Abf[18][264];
  int m0=(blockIdx.x>>1)*16, nh=blockIdx.x&1, tid=threadIdx.x, b=m0>>8, s0=m0&255;
  for(int it=0;it<18;it++){
    int sI=s0-1+it;
    float v=(sI>=0&&sI<256)? V2[(unsigned)(b*256+sI)*256u+tid] : 0.0f;
    Abf[it][tid]=bf16h(v);
  }
  __syncthreads();
  int w=tid>>6, lane=tid&63, lq=lane>>4, lm=lane&15;
  ffrag acc[2];
  #pragma unroll
  for(int tt=0;tt<2;tt++){ acc[tt][0]=0;acc[tt][1]=0;acc[tt][2]=0;acc[tt][3]=0; }
  for(int k3=0;k3<3;k3++){
    const unsigned short* wb3=wb+(unsigned)k3*65536u;
    #pragma unroll
    for(int kt=0;kt<8;kt++){
      bfrag af=*(const bfrag*)&Abf[lm+k3][kt*32+lq*8];
      #pragma unroll
      for(int tt=0;tt<2;tt++){
        int nt=nh*8+w*2+tt;
        bfrag bf=*(const bfrag*)(wb3+((((unsigned)(nt*8+kt))*64u+(unsigned)lane)<<3));
        acc[tt]=__builtin_amdgcn_mfma_f32_16x16x32_bf16(af,bf,acc[tt],0,0,0);
      }
    }
  }
  float al=ws[WS_ALPHA+b];
  unsigned short* stt=(unsigned short*)(ws+WS_STT);
  #pragma unroll
  for(int tt=0;tt<2;tt++){
    int n=nh*128+w*32+tt*16+lm;
    float bn=p2b[n];
    unsigned short o0=bf16h((acc[tt][0]+bn)*al);
    unsigned short o1=bf16h((acc[tt][1]+bn)*al);
    unsigned short o2=bf16h((acc[tt][2]+bn)*al);
    unsigned short o3=bf16h((acc[tt][3]+bn)*al);
    *(uint2*)&stt[((unsigned)(b*256+n)<<8)+(unsigned)(s0+lq*4)]=
      make_uint2((unsigned)o0|((unsigned)o1<<16),(unsigned)o2|((unsigned)o3<<16));
  }
}

// ---------------- Cv = LN16(relu(conv1d(alpha*V, cw)+cwb)) (fp32) ----------------
__global__ __launch_bounds__(256) void k_cv(const float* __restrict__ V2, const float* __restrict__ cwk,
    const float* __restrict__ cwb, const float* __restrict__ cwg, const float* __restrict__ cwbe,
    float* __restrict__ ws){
  __shared__ float Vt[18][SS];
  int b=blockIdx.x>>4, tile=blockIdx.x&15, tid=threadIdx.x;
  int sbase=tile*16;
  float al=ws[WS_ALPHA+b];
  for(int rr=0;rr<18;rr++){
    int s=sbase-1+rr;
    Vt[rr][tid]=(s>=0&&s<SS)?al*V2[(b*SS+s)*HH+tid]:0.0f;
  }
  __syncthreads();
  int sl=tid>>4, oc=tid&15;
  float a0=cwb[oc],a1=0.f,a2=0.f,a3=0.f;
  for(int k3=0;k3<3;k3++){
    const float* vp=&Vt[sl+k3][0];
    const float* wpp=cwk+(unsigned)k3*HH*CWW+oc;
    for(int c=0;c<HH;c+=4){
      a0+=vp[c+0]*wpp[(c+0)*CWW];
      a1+=vp[c+1]*wpp[(c+1)*CWW];
      a2+=vp[c+2]*wpp[(c+2)*CWW];
      a3+=vp[c+3]*wpp[(c+3)*CWW];
    }
  }
  float acc=fmaxf((a0+a1)+(a2+a3),0.0f);
  float ssum=acc, qsum=acc*acc;
  for(int off=8;off;off>>=1){ ssum+=__shfl_xor(ssum,off); qsum+=__shfl_xor(qsum,off); }
  float mean=ssum*(1.0f/CWW), var=qsum*(1.0f/CWW)-mean*mean;
  float cv=(acc-mean)*rsqrtf(var+1e-5f)*cwg[oc]+cwbe[oc];
  ws[WS_CV+(unsigned)(b*SS+sbase+sl)*CWW+oc]=cv;
}

// ---------------- CP + affine fast-path tables ----------------
__global__ __launch_bounds__(256) void k_cp(const float* __restrict__ mkb1k, const float* __restrict__ mkb1b,
    float* __restrict__ ws){
  __shared__ float CvL[258][17];
  __shared__ float k1c[3][3][CWW][NOC];
  __shared__ float kab[3][3][2][NOC];
  __shared__ float skE[258], ekE[258], fiE[258];
  int b=blockIdx.x, tid=threadIdx.x;
  for(int i=tid;i<3*3*CWW*NOC;i+=256){
    int oc=i&15, ic=(i>>4)&15, kk=i>>8;
    int kw=kk%3, kh=kk/3;
    k1c[kh][kw][ic][oc]=mkb1k[((kh*3+kw)*18+2+ic)*NOC+oc];
  }
  for(int i=tid;i<3*3*2*NOC;i+=256){
    int oc=i&15, ch=(i>>4)&1, kk=i>>5;
    int kw=kk%3, kh=kk/3;
    kab[kh][kw][ch][oc]=mkb1k[((kh*3+kw)*18+ch)*NOC+oc];
  }
  for(int i=tid;i<SS*CWW;i+=256) CvL[1+(i>>4)][i&15]=ws[WS_CV+(unsigned)b*SS*CWW+i];
  if(tid<CWW){ CvL[0][tid]=0.f; CvL[257][tid]=0.f; }
  if(tid<258){
    float sk=0.f, ek=0.f, fi=0.f;
    if(tid>=1 && tid<=SS){
      sk=ws[WS_SK+b*SS+tid-1];
      ek=ws[WS_EK+b*SS+tid-1];
      fi=(ws[WS_TMASK+b*SS+tid-1]!=0.0f)?0.0f:1.0f;
    }
    skE[tid]=sk; ekE[tid]=ek; fiE[tid]=fi;
  }
  __syncthreads();
  float* cpg=ws+WS_CP+(unsigned)b*3*SS*NOC;
  float ccv[16],ssv[16],cci[16],ssi[16];
  #pragma unroll
  for(int oc=0;oc<NOC;oc++){ float bb=mkb1b[oc]; ccv[oc]=bb; cci[oc]=bb; ssv[oc]=0.f; ssi[oc]=0.f; }
  for(int dt=0;dt<3;dt++){
    float acc[NOC];
    #pragma unroll
    for(int oc=0;oc<NOC;oc++) acc[oc]=0.f;
    #pragma unroll
    for(int ds=0;ds<3;ds++){
      #pragma unroll
      for(int ic=0;ic<CWW;ic++){
        float v=CvL[tid+ds][ic];
        #pragma unroll
        for(int oc=0;oc<NOC;oc++) acc[oc]+=v*k1c[dt][ds][ic][oc];
      }
    }
    for(int oc=0;oc<NOC;oc++) cpg[(unsigned)(dt*SS+tid)*NOC+oc]=acc[oc];
    float va[16],vb[16],ia[16],ib2[16];
    #pragma unroll
    for(int oc=0;oc<NOC;oc++){ va[oc]=0.f; vb[oc]=0.f; ia[oc]=0.f; ib2[oc]=0.f; }
    #pragma unroll
    for(int ds=0;ds<3;ds++){
      int j=tid+ds;
      float inb=(j>=1&&j<=SS)?1.0f:0.0f;
      float fb=fiE[j];
      float skv=skE[j], ekv=ekE[j];
      #pragma unroll
      for(int oc=0;oc<NOC;oc++){
        float ka=kab[dt][ds][0][oc], kb=kab[dt][ds][1][oc];
        float d=ka-kb, e=kb*ekv-ka*skv;
        va[oc]+=inb*d; vb[oc]+=inb*e; ia[oc]+=fb*d; ib2[oc]+=fb*e;
      }
    }
    float dtf=(float)dt;
    #pragma unroll
    for(int oc=0;oc<NOC;oc++){
      ccv[oc]+=acc[oc]+vb[oc]+dtf*va[oc]; ssv[oc]+=va[oc];
      cci[oc]+=acc[oc]+ib2[oc]+dtf*ia[oc]; ssi[oc]+=ia[oc];
    }
  }
  unsigned base=(unsigned)(b*SS+tid)*16u;
  for(int oc=0;oc<NOC;oc++){
    ws[WS_CCV+base+oc]=ccv[oc];
    ws[WS_SSV+base+oc]=ssv[oc];
    ws[WS_CCI+base+oc]=cci[oc];
    ws[WS_SSI+base+oc]=ssi[oc];
  }
}

// ---------------- stage B: conv1 -> conv2(MFMA) -> softmax -> Wmat ----------------
__global__ __launch_bounds__(256,3) void k_stageB(
    const float* __restrict__ ws, const float* __restrict__ mkb1k, const float* __restrict__ mkb1b,
    const float* __restrict__ mkb2k, const float* __restrict__ mkb2b,
    const float* __restrict__ lww, const float* __restrict__ lwb,
    float* __restrict__ outp){
  __shared__ short ringh[3][258][RB];
  __shared__ float skL[258], ekL[258], finL[258];
  __shared__ float wscL[SS];
  __shared__ float red[16];
  int bx=blockIdx.x, b=bx/125, chunk=bx%125, t0=chunk*8, tid=threadIdx.x;
  int wid=tid>>6, lane=tid&63;
  int lq=lane>>4, lm=lane&15;
  if(tid<258){
    float sk=0.f, ek=0.f, fin=0.f;
    if(tid>=1 && tid<=SS){
      sk=ws[WS_SK+b*SS+tid-1];
      ek=ws[WS_EK+b*SS+tid-1];
      fin=(ws[WS_TMASK+b*SS+tid-1]!=0.0f)?0.0f:1.0f;
    }
    skL[tid]=sk; ekL[tid]=ek; finL[tid]=fin;
  }
  if(tid<72){
    int sl=tid/24, rem=tid%24;
    int row=(rem<12)?0:257, c=(rem%12)*2;
    *(int*)&ringh[sl][row][c]=0;
  }
  int mel=((const int*)ws)[WS_MELI+b];
  __syncthreads();

  const float* cpb=ws+WS_CP+(unsigned)b*3*SS*NOC;

  unsigned offA[5]; int dtL[5], zgL[5];
  bfrag bfw[5];
  {
    #pragma unroll
    for(int i=0;i<5;i++){
      int g=4*i+lq;
      int dt,ds,hf,zg;
      if(g<18){ dt=g/6; int rm=g-6*dt; ds=rm>>1; hf=rm&1; zg=0; }
      else { dt=0; ds=0; hf=0; zg=1; }
      int srow=wid*64+lm+ds;
      offA[i]=(unsigned)((srow*RB+8*hf)*2);
      dtL[i]=dt; zgL[i]=zg;
      int pk[4];
      if(!zg){
        #pragma unroll
        for(int j=0;j<4;j++){
          unsigned u0=bf16rne(mkb2k[(8*g+2*j)*NOC+lm]);
          unsigned u1=bf16rne(mkb2k[(8*g+2*j+1)*NOC+lm]);
          pk[j]=(int)((u0>>16)|(u1&0xffff0000u));
        }
      } else pk[0]=pk[1]=pk[2]=pk[3]=0;
      bfw[i]=__builtin_bit_cast(bfrag, make_int4(pk[0],pk[1],pk[2],pk[3]));
    }
  }
  float b2v=mkb2b[lm];
  float lwwv=lww[lm];
  float lwb0=lwb[0];
  const char* ringB=(const char*)&ringh[0][0][0];
  bfrag azero={};

  auto conv1row=[&](int T){
    int s=tid;
    float acc[NOC];
    bool fv=(T>=1)&&(T<=998)&&(T+1<mel);
    bool fi=(T>=2)&&(T<=998)&&(T-1>=mel);
    if(fv||fi){
      const float* cc=ws+(fv?WS_CCV:WS_CCI)+(unsigned)(b*SS+s)*16u;
      const float* s2=ws+(fv?WS_SSV:WS_SSI)+(unsigned)(b*SS+s)*16u;
      float Tf=(float)T;
      #pragma unroll
      for(int q=0;q<4;q++){
        float4 c4=((const float4*)cc)[q];
        float4 s4=((const float4*)s2)[q];
        acc[4*q+0]=c4.x+Tf*s4.x; acc[4*q+1]=c4.y+Tf*s4.y;
        acc[4*q+2]=c4.z+Tf*s4.z; acc[4*q+3]=c4.w+Tf*s4.w;
      }
    } else {
      #pragma unroll
      for(int oc=0;oc<NOC;oc++) acc[oc]=mkb1b[oc];
      #pragma unroll
      for(int dt=0;dt<3;dt++){
        int tr=T+dt-1;
        if(tr<0||tr>=MLEN) continue;
        bool valid=(tr<mel);
        float tt=(float)(tr+1);
        float gg[3], hh[3];
        #pragma unroll
        for(int ds=0;ds<3;ds++){
          int j=s+ds;
          float f = valid ? ((j>=1&&j<=SS)?1.0f:0.0f) : finL[j];
          gg[ds]=f*(tt-skL[j]);
          hh[ds]=f*(ekL[j]-tt);
        }
        const float* cpr=cpb+(unsigned)(dt*SS+s)*NOC;
        float4 c0=((const float4*)cpr)[0], c1=((const float4*)cpr)[1];
        float4 c2=((const float4*)cpr)[2], c3=((const float4*)cpr)[3];
        acc[0]+=c0.x; acc[1]+=c0.y; acc[2]+=c0.z; acc[3]+=c0.w;
        acc[4]+=c1.x; acc[5]+=c1.y; acc[6]+=c1.z; acc[7]+=c1.w;
        acc[8]+=c2.x; acc[9]+=c2.y; acc[10]+=c2.z; acc[11]+=c2.w;
        acc[12]+=c3.x; acc[13]+=c3.y; acc[14]+=c3.z; acc[15]+=c3.w;
        #pragma unroll
        for(int ds=0;ds<3;ds++){
          const float* kA=mkb1k+((dt*3+ds)*18+0)*NOC;
          const float* kB=mkb1k+((dt*3+ds)*18+1)*NOC;
          #pragma unroll
          for(int oc=0;oc<NOC;oc++) acc[oc]+=gg[ds]*kA[oc]+hh[ds]*kB[oc];
        }
      }
    }
    int slot=T%3;
    int pk[8];
    #pragma unroll
    for(int j=0;j<8;j++){
      float x0=acc[2*j], x1=acc[2*j+1];
      float s0=x0/(1.0f+__expf(-x0));
      float s1=x1/(1.0f+__expf(-x1));
      unsigned u0=bf16rne(s0), u1=bf16rne(s1);
      pk[j]=(int)((u0>>16)|(u1&0xffff0000u));
    }
    int4* dst=(int4*)&ringh[slot][s+1][0];
    dst[0]=make_int4(pk[0],pk[1],pk[2],pk[3]);
    dst[1]=make_int4(pk[4],pk[5],pk[6],pk[7]);
  };

  if(t0>0) conv1row(t0-1);
  conv1row(t0);

  #pragma unroll 1
  for(int r=0;r<8;r++){
    int t=t0+r;
    if(t+1<MLEN) conv1row(t+1);
    __syncthreads();
    int tmod=t%3;
    ffrag acc2[4];
    #pragma unroll
    for(int tt=0;tt<4;tt++){ acc2[tt][0]=b2v; acc2[tt][1]=b2v; acc2[tt][2]=b2v; acc2[tt][3]=b2v; }
    #pragma unroll
    for(int i=0;i<5;i++){
      int dt=dtL[i];
      int x=tmod+dt+2; x=(x>=3)?x-3:x; x=(x>=3)?x-3:x;
      int tr=t+dt-1;
      bool av=((unsigned)tr<(unsigned)MLEN)&&(!zgL[i]);
      const char* rp=ringB+(unsigned)x*(258u*RB*2u)+offA[i];
      #pragma unroll
      for(int tt=0;tt<4;tt++){
        int4 ra=*(const int4*)(rp+tt*(16*RB*2));
        bfrag a=av?__builtin_bit_cast(bfrag,ra):azero;
        acc2[tt]=__builtin_amdgcn_mfma_f32_16x16x32_bf16(a,bfw[i],acc2[tt],0,0,0);
      }
    }
    #pragma unroll
    for(int tt=0;tt<4;tt++){
      float out4[4];
      #pragma unroll
      for(int q=0;q<4;q++){
        float xx=acc2[tt][q];
        float pv=(xx/(1.0f+__expf(-xx)))*lwwv;
        pv+=__shfl_xor(pv,1); pv+=__shfl_xor(pv,2); pv+=__shfl_xor(pv,4); pv+=__shfl_xor(pv,8);
        out4[q]=pv+lwb0;
      }
      if(lm==0){
        *(float4*)&wscL[wid*64+tt*16+lq*4]=make_float4(out4[0],out4[1],out4[2],out4[3]);
      }
    }
    __syncthreads();
    float fm=finL[tid+1];
    float wsc=wscL[tid];
    float val=(fm!=0.0f)?wsc:-3.0e38f;
    float mx=val;
    for(int off=32;off;off>>=1) mx=fmaxf(mx,__shfl_down(mx,off));
    if(lane==0) red[wid]=mx;
    __syncthreads();
    mx=fmaxf(fmaxf(red[0],red[1]),fmaxf(red[2],red[3]));
    float e=(fm!=0.0f)?__expf(wsc-mx):0.0f;
    float sm=e;
    for(int off=32;off;off>>=1) sm+=__shfl_down(sm,off);
    if(lane==0) red[8+wid]=sm;
    __syncthreads();
    sm=red[8]+red[9]+red[10]+red[11];
    outp[OUT_W+(unsigned)(b*MLEN+t)*SS+tid]=e/sm;
    __syncthreads();
  }
}

// ---------------- up = W @ sT (MFMA) + LN + mel mask ----------------
__global__ __launch_bounds__(256) void k_up(const float* __restrict__ ws,
    const float* __restrict__ lng, const float* __restrict__ lnb, float* __restrict__ outp){
  __shared__ unsigned short Wbf[16][264];
  __shared__ float UpL[16][264];
  __shared__ float gb[2][256];
  int bx=blockIdx.x, b=bx/63, tile=bx%63, t0=tile*16, tid=threadIdx.x;
  gb[0][tid]=lng[tid]; gb[1][tid]=lnb[tid];
  for(int it=0;it<16;it++){
    int t=t0+it;
    float v=(t<MLEN)? outp[OUT_W+(unsigned)(b*MLEN+t)*256u+tid] : 0.0f;
    Wbf[it][tid]=bf16h(v);
  }
  int mel=((const int*)ws)[WS_MELI+b];
  __syncthreads();
  int w=tid>>6, lane=tid&63, lq=lane>>4, lm=lane&15;
  const unsigned short* stt=(const unsigned short*)(ws+WS_STT)+(unsigned)b*65536u;
  ffrag acc[4];
  #pragma unroll
  for(int tt=0;tt<4;tt++){ acc[tt][0]=0;acc[tt][1]=0;acc[tt][2]=0;acc[tt][3]=0; }
  #pragma unroll
  for(int kt=0;kt<8;kt++){
    bfrag af=*(const bfrag*)&Wbf[lm][kt*32+lq*8];
    #pragma unroll
    for(int tt=0;tt<4;tt++){
      int n=w*64+tt*16+lm;
      bfrag bf=*(const bfrag*)(stt+((unsigned)n<<8)+(unsigned)(kt*32+lq*8));
      acc[tt]=__builtin_amdgcn_mfma_f32_16x16x32_bf16(af,bf,acc[tt],0,0,0);
    }
  }
  #pragma unroll
  for(int tt=0;tt<4;tt++){
    #pragma unroll
    for(int reg=0;reg<4;reg++)
      UpL[lq*4+reg][w*64+tt*16+lm]=acc[tt][reg];
  }
  __syncthreads();
  int r=tid>>4, seg=tid&15;
  float s=0.f,q=0.f;
  #pragma unroll
  for(int j4=0;j4<4;j4++){
    float4 v=*(const float4*)&UpL[r][seg*16+j4*4];
    s+=v.x+v.y+v.z+v.w; q+=v.x*v.x+v.y*v.y+v.z*v.z+v.w*v.w;
  }
  s+=__shfl_xor(s,1); q+=__shfl_xor(q,1);
  s+=__shfl_xor(s,2); q+=__shfl_xor(q,2);
  s+=__shfl_xor(s,4); q+=__shfl_xor(q,4);
  s+=__shfl_xor(s,8); q+=__shfl_xor(q,8);
  float mean=s*(1.0f/256.0f), rstd=rsqrtf(q*(1.0f/256.0f)-mean*mean+1e-5f);
  int t=t0+r;
  if(t<MLEN){
    bool vld=(t<mel);
    #pragma unroll
    for(int j4=0;j4<4;j4++){
      int c=seg*16+j4*4;
      float4 v=*(const float4*)&UpL[r][c];
      float4 o;
      o.x=vld?((v.x-mean)*rstd*gb[0][c+0]+gb[1][c+0]):0.0f;
      o.y=vld?((v.y-mean)*rstd*gb[0][c+1]+gb[1][c+1]):0.0f;
      o.z=vld?((v.z-mean)*rstd*gb[0][c+2]+gb[1][c+2]):0.0f;
      o.w=vld?((v.w-mean)*rstd*gb[0][c+3]+gb[1][c+3]):0.0f;
      *(float4*)&outp[OUT_UP+(unsigned)(b*MLEN+t)*256u+c]=o;
    }
  }
}

extern "C" void kernel_launch(void* const* d_in, const int* in_sizes, int n_in,
                              void* d_out, int out_size, void* d_ws, size_t ws_size,
                              hipStream_t stream){
  const float* ce   =(const float*)d_in[0];
  const float* spk  =(const float*)d_in[1];
  const float* rhy  =(const float*)d_in[2];
  const float* sdo  =(const float*)d_in[3];
  const void*  tmr  =d_in[4];
  const float* in_w =(const float*)d_in[5];
  const float* in_b =(const float*)d_in[6];
  const float* l0lg =(const float*)d_in[7];
  const float* l0lb =(const float*)d_in[8];
  const float* l0gw =(const float*)d_in[9];
  const float* l0gb =(const float*)d_in[10];
  const float* l0dw =(const float*)d_in[11];
  const float* l0ow =(const float*)d_in[12];
  const float* l0ob =(const float*)d_in[13];
  const float* l1lg =(const float*)d_in[14];
  const float* l1lb =(const float*)d_in[15];
  const float* l1gw =(const float*)d_in[16];
  const float* l1gb =(const float*)d_in[17];
  const float* l1dw =(const float*)d_in[18];
  const float* l1ow =(const float*)d_in[19];
  const float* l1ob =(const float*)d_in[20];
  const float* p1w  =(const float*)d_in[21];
  const float* p1b  =(const float*)d_in[22];
  const float* p2k  =(const float*)d_in[23];
  const float* p2b  =(const float*)d_in[24];
  const float* cwk  =(const float*)d_in[25];
  const float* cwb  =(const float*)d_in[26];
  const float* cwg  =(const float*)d_in[27];
  const float* cwbe =(const float*)d_in[28];
  const float* m1k  =(const float*)d_in[29];
  const float* m1b  =(const float*)d_in[30];
  const float* m2k  =(const float*)d_in[31];
  const float* m2b  =(const float*)d_in[32];
  const float* lww  =(const float*)d_in[33];
  const float* lwbp =(const float*)d_in[34];
  const float* lng  =(const float*)d_in[35];
  const float* lnb  =(const float*)d_in[36];
  float* ws=(float*)d_ws;
  float* outp=(float*)d_out;
  const unsigned short* wbb=(const unsigned short*)(ws+WS_WB);
  unsigned short* hb=(unsigned short*)(ws+WS_HB);

  k_mask   <<<1,256,0,stream>>>(tmr, ws);
  k_prep   <<<256,256,0,stream>>>(in_w, l0gw, l1gw, l0ow, l1ow, p2k, ws);
  k_inproj2<<<256,256,0,stream>>>(ce, spk, wbb+PK_IN, in_b, ws);
  k_glu2   <<<256,256,0,stream>>>(ws+WS_X,  wbb+PK_GLU0, l0gb, l0lg, l0lb, ws+WS_TMASK, hb);
  k_dwout2 <<<256,256,0,stream>>>(hb, ws+WS_X,  wbb+PK_OUT0, l0dw, l0ob, ws+WS_TMASK, ws+WS_V1);
  k_glu2   <<<256,256,0,stream>>>(ws+WS_V1, wbb+PK_GLU1, l1gb, l1lg, l1lb, ws+WS_TMASK, hb);
  k_dwout2 <<<256,256,0,stream>>>(hb, ws+WS_V1, wbb+PK_OUT1, l1dw, l1ob, ws+WS_TMASK, ws+WS_V2);
  k_dur    <<<8,256,0,stream>>>(ws+WS_V2, p1w, p1b, sdo, rhy, ws, outp);
  k_T2     <<<256,256,0,stream>>>(ws+WS_V2, wbb+PK_P2, p2b, ws);
  k_cv     <<<128,256,0,stream>>>(ws+WS_V2, cwk, cwb, cwg, cwbe, ws);
  k_cp     <<<8,256,0,stream>>>(m1k, m1b, ws);
  k_stageB <<<1000,256,0,stream>>>(ws, m1k, m1b, m2k, m2b, lww, lwbp, outp);
  k_up     <<<504,256,0,stream>>>(ws, lng, lnb, outp);
}

// Round 5
// 310.623 us; speedup vs baseline: 1.9145x; 1.0565x over previous
//
#include <hip/hip_runtime.h>
#include <math.h>

#define SS 256
#define HH 256
#define MLEN 1000
#define CWW 16
#define NOC 16
#define RB 24          // ring row stride in bf16 elems (48B, 16B-aligned)

typedef __attribute__((ext_vector_type(8))) short bfrag;
typedef __attribute__((ext_vector_type(4))) float ffrag;

// float-indexed workspace offsets
#define WS_V2     1048576u
#define WS_STT    1835008u    // sTt bf16 [8][256 h][256 s]
#define WS_WB     2097152u    // packed bf16 weights
#define WS_CCV    2424832u    // [8][256][16]
#define WS_SSV    2457600u
#define WS_CCI    2490368u
#define WS_SSI    2523136u
#define WS_CP     2555904u    // [8][3][256][16]
#define WS_CV     2654208u    // [8][256][16]
#define WS_EK     2686976u
#define WS_SK     2689024u
#define WS_ALPHA  2691072u
#define WS_MELI   2691080u
#define WS_TMASK  2691088u

// packed-weight offsets in shorts relative to (unsigned short*)(ws+WS_WB)
#define PK_IN     0u
#define PK_GLU0   65536u
#define PK_GLU1   196608u
#define PK_OUT0   327680u
#define PK_OUT1   393216u
#define PK_P2     458752u

// output offsets
#define OUT_UP    0u
#define OUT_W     2048000u
#define OUT_ALPHA 4096000u
#define OUT_MLEN  4096008u
#define OUT_MMASK 4096016u

__device__ __forceinline__ unsigned bf16rne(float x){
  unsigned u=__float_as_uint(x);
  u += 0x7fffu + ((u>>16)&1u);
  return u;
}
__device__ __forceinline__ unsigned short bf16h(float x){ return (unsigned short)(bf16rne(x)>>16); }
__device__ __forceinline__ float bf2f(unsigned short u){ return __uint_as_float(((unsigned)u)<<16); }
__device__ __forceinline__ unsigned frag_idx(int k,int n,int KT){
  return (unsigned)(((((n>>4)*KT+(k>>5))*64 + ((k>>3)&3)*16 + (n&15))<<3) + (k&7));
}

// ---------------- mask canonicalization + weight packing (one launch) ----------------
__global__ __launch_bounds__(256) void k_prepmask(const void* __restrict__ traw,
    const float* __restrict__ in_w,
    const float* __restrict__ g0, const float* __restrict__ g1,
    const float* __restrict__ o0, const float* __restrict__ o1,
    const float* __restrict__ p2k, float* __restrict__ ws){
  int tid=threadIdx.x;
  if(blockIdx.x==256){
    __shared__ int s_fu, s_ff, s_nz;
    const unsigned char* mb=(const unsigned char*)traw;
    const unsigned int*  mw=(const unsigned int*)traw;
    if(tid==0){s_fu=0;s_ff=0;s_nz=0;}
    __syncthreads();
    int fu=0,ff=0,nz=0;
    for(int w=tid;w<512;w+=256){
      unsigned int v=mw[w];
      if(v){ nz=1; if(v==0x3F800000u) ff=1; else if(v&0xFFFFFF00u) fu=1; }
    }
    if(fu) atomicOr(&s_fu,1);
    if(ff) atomicOr(&s_ff,1);
    if(nz) atomicOr(&s_nz,1);
    __syncthreads();
    int words = (s_ff || (!s_fu && s_nz));
    for(int i=tid;i<2048;i+=256){
      unsigned int v = words ? mw[i] : (unsigned int)mb[i];
      ws[WS_TMASK+i] = v ? 1.0f : 0.0f;
    }
    return;
  }
  unsigned short* wb=(unsigned short*)(ws+WS_WB);
  int gid=blockIdx.x*256+tid, stride=65536;
  for(int i=gid;i<65536;i+=stride){ int k=i>>8,n=i&255; wb[PK_IN  +frag_idx(k,n,8)]=bf16h(in_w[i]); }
  for(int i=gid;i<131072;i+=stride){ int k=i>>9,n=i&511; wb[PK_GLU0+frag_idx(k,n,8)]=bf16h(g0[i]); }
  for(int i=gid;i<131072;i+=stride){ int k=i>>9,n=i&511; wb[PK_GLU1+frag_idx(k,n,8)]=bf16h(g1[i]); }
  for(int i=gid;i<65536;i+=stride){ int k=i>>8,n=i&255; wb[PK_OUT0+frag_idx(k,n,8)]=bf16h(o0[i]); }
  for(int i=gid;i<65536;i+=stride){ int k=i>>8,n=i&255; wb[PK_OUT1+frag_idx(k,n,8)]=bf16h(o1[i]); }
  for(int i=gid;i<196608;i+=stride){ int k3=i>>16,r=i&65535,k=r>>8,n=r&255;
    wb[PK_P2+(unsigned)k3*65536u+frag_idx(k,n,8)]=bf16h(p2k[i]); }
}

// ---------------- fused front-end: inproj -> LConv0 -> LConv1 -> V2 ----------------
// 8-row output tile, +-2 halo recompute, all intermediates in LDS.
__global__ __launch_bounds__(256) void k_front(
    const float* __restrict__ ce, const float* __restrict__ spk,
    const unsigned short* __restrict__ wb, const float* __restrict__ in_b,
    const float* __restrict__ g0b, const float* __restrict__ ln0g, const float* __restrict__ ln0b,
    const float* __restrict__ dw0, const float* __restrict__ o0b,
    const float* __restrict__ g1b, const float* __restrict__ ln1g, const float* __restrict__ ln1b,
    const float* __restrict__ dw1, const float* __restrict__ o1b,
    const float* __restrict__ tmask, float* __restrict__ V2){
  __shared__ unsigned short Abf[16][264];
  __shared__ unsigned short Hb[16][264];
  __shared__ float Xf[16][264];
  __shared__ float Vf[16][264];
  __shared__ float dws[2][3][256];
  __shared__ float tmL[20];
  int b=blockIdx.x>>5, tile=blockIdx.x&31, s0=tile*8, tid=threadIdx.x;
  int w=tid>>6, lane=tid&63, lq=lane>>4, lm=lane&15;
  {
    float d0=dw0[tid*3],d1=dw0[tid*3+1],d2=dw0[tid*3+2];
    float mx=fmaxf(d0,fmaxf(d1,d2));
    float e0=__expf(d0-mx),e1=__expf(d1-mx),e2=__expf(d2-mx);
    float inv=1.0f/(e0+e1+e2);
    dws[0][0][tid]=e0*inv; dws[0][1][tid]=e1*inv; dws[0][2][tid]=e2*inv;
    d0=dw1[tid*3];d1=dw1[tid*3+1];d2=dw1[tid*3+2];
    mx=fmaxf(d0,fmaxf(d1,d2));
    e0=__expf(d0-mx);e1=__expf(d1-mx);e2=__expf(d2-mx);
    inv=1.0f/(e0+e1+e2);
    dws[1][0][tid]=e0*inv; dws[1][1][tid]=e1*inv; dws[1][2][tid]=e2*inv;
  }
  if(tid<18){
    int sI=s0-2+tid;
    tmL[tid]=(sI>=0&&sI<256)? tmask[b*256+sI] : 1.0f;
  }
  // phase1: stage concat(ce,spk) rows s0-2..s0+9 as bf16
  for(int it=0;it<16;it++){
    float v=0.f;
    int sI=s0-2+it;
    if(it<12 && sI>=0 && sI<256){
      int m=b*256+sI;
      v=(tid<192)? ce[m*192+tid] : spk[b*64+tid-192];
    }
    Abf[it][tid]=bf16h(v);
  }
  __syncthreads();
  // phase2: inproj MFMA -> Xf (+bias)
  {
    ffrag acc[4];
    #pragma unroll
    for(int j=0;j<4;j++){acc[j][0]=0;acc[j][1]=0;acc[j][2]=0;acc[j][3]=0;}
    #pragma unroll
    for(int kt=0;kt<8;kt++){
      bfrag af=*(const bfrag*)&Abf[lm][kt*32+lq*8];
      #pragma unroll
      for(int j=0;j<4;j++){
        int nt=w*4+j;
        bfrag bf=*(const bfrag*)(wb+PK_IN+((((unsigned)(nt*8+kt))*64u+(unsigned)lane)<<3));
        acc[j]=__builtin_amdgcn_mfma_f32_16x16x32_bf16(af,bf,acc[j],0,0,0);
      }
    }
    #pragma unroll
    for(int j=0;j<4;j++){
      int n=w*64+j*16+lm;
      float bn=in_b[n];
      #pragma unroll
      for(int reg=0;reg<4;reg++) Xf[lq*4+reg][n]=acc[j][reg]+bn;
    }
  }
  __syncthreads();
  // phase3: LN0 -> Abf bf16
  {
    int r=tid>>4, seg=tid&15;
    if(r<12){
      float s=0.f,q=0.f;
      #pragma unroll
      for(int j4=0;j4<4;j4++){
        float4 v=*(const float4*)&Xf[r][seg*16+j4*4];
        s+=v.x+v.y+v.z+v.w; q+=v.x*v.x+v.y*v.y+v.z*v.z+v.w*v.w;
      }
      s+=__shfl_xor(s,1); q+=__shfl_xor(q,1);
      s+=__shfl_xor(s,2); q+=__shfl_xor(q,2);
      s+=__shfl_xor(s,4); q+=__shfl_xor(q,4);
      s+=__shfl_xor(s,8); q+=__shfl_xor(q,8);
      float mean=s*(1.0f/256.0f), rstd=rsqrtf(q*(1.0f/256.0f)-mean*mean+1e-5f);
      #pragma unroll
      for(int j4=0;j4<4;j4++){
        int c=seg*16+j4*4;
        float4 v=*(const float4*)&Xf[r][c];
        unsigned short q0=bf16h((v.x-mean)*rstd*ln0g[c+0]+ln0b[c+0]);
        unsigned short q1=bf16h((v.y-mean)*rstd*ln0g[c+1]+ln0b[c+1]);
        unsigned short q2=bf16h((v.z-mean)*rstd*ln0g[c+2]+ln0b[c+2]);
        unsigned short q3=bf16h((v.w-mean)*rstd*ln0g[c+3]+ln0b[c+3]);
        *(uint2*)&Abf[r][c]=make_uint2((unsigned)q0|((unsigned)q1<<16),(unsigned)q2|((unsigned)q3<<16));
      }
    } else {
      #pragma unroll
      for(int j4=0;j4<4;j4++) *(uint2*)&Abf[r][seg*16+j4*4]=make_uint2(0,0);
    }
  }
  __syncthreads();
  // phase4: glu0 -> Hb (masked)
  {
    ffrag aa[4],ag[4];
    #pragma unroll
    for(int j=0;j<4;j++){aa[j][0]=0;aa[j][1]=0;aa[j][2]=0;aa[j][3]=0;
                         ag[j][0]=0;ag[j][1]=0;ag[j][2]=0;ag[j][3]=0;}
    #pragma unroll
    for(int kt=0;kt<8;kt++){
      bfrag af=*(const bfrag*)&Abf[lm][kt*32+lq*8];
      #pragma unroll
      for(int j=0;j<4;j++){
        int nta=w*4+j, ntg=nta+16;
        bfrag bfa=*(const bfrag*)(wb+PK_GLU0+((((unsigned)(nta*8+kt))*64u+(unsigned)lane)<<3));
        bfrag bfg=*(const bfrag*)(wb+PK_GLU0+((((unsigned)(ntg*8+kt))*64u+(unsigned)lane)<<3));
        aa[j]=__builtin_amdgcn_mfma_f32_16x16x32_bf16(af,bfa,aa[j],0,0,0);
        ag[j]=__builtin_amdgcn_mfma_f32_16x16x32_bf16(af,bfg,ag[j],0,0,0);
      }
    }
    __syncthreads();   // Abf reads done (reused next phase)
    #pragma unroll
    for(int j=0;j<4;j++){
      int n=w*64+j*16+lm;
      float ba=g0b[n], bg=g0b[n+256];
      #pragma unroll
      for(int reg=0;reg<4;reg++){
        int row=lq*4+reg;
        float a=aa[j][reg]+ba, g=ag[j][reg]+bg;
        float hv=a*(1.0f/(1.0f+__expf(-g)));
        if(row>=12||tmL[row]!=0.0f) hv=0.0f;
        Hb[row][n]=bf16h(hv);
      }
    }
  }
  __syncthreads();
  // phase5: dwconv0 -> Abf rows 0..9
  {
    float w0=dws[0][0][tid],w1=dws[0][1][tid],w2=dws[0][2][tid];
    for(int r=0;r<10;r++){
      float a=w0*bf2f(Hb[r][tid])+w1*bf2f(Hb[r+1][tid])+w2*bf2f(Hb[r+2][tid]);
      Abf[r][tid]=bf16h(a);
    }
    for(int r=10;r<16;r++) Abf[r][tid]=0;
  }
  __syncthreads();
  // phase6: outproj0 + residual + mask -> Vf rows 0..9
  {
    ffrag acc[4];
    #pragma unroll
    for(int j=0;j<4;j++){acc[j][0]=0;acc[j][1]=0;acc[j][2]=0;acc[j][3]=0;}
    #pragma unroll
    for(int kt=0;kt<8;kt++){
      bfrag af=*(const bfrag*)&Abf[lm][kt*32+lq*8];
      #pragma unroll
      for(int j=0;j<4;j++){
        int nt=w*4+j;
        bfrag bf=*(const bfrag*)(wb+PK_OUT0+((((unsigned)(nt*8+kt))*64u+(unsigned)lane)<<3));
        acc[j]=__builtin_amdgcn_mfma_f32_16x16x32_bf16(af,bf,acc[j],0,0,0);
      }
    }
    #pragma unroll
    for(int j=0;j<4;j++){
      int n=w*64+j*16+lm;
      float bn=o0b[n];
      #pragma unroll
      for(int reg=0;reg<4;reg++){
        int row=lq*4+reg;
        float v=(row<10 && tmL[row+1]==0.0f)? acc[j][reg]+bn+Xf[row+1][n] : 0.0f;
        Vf[row][n]=v;
      }
    }
  }
  __syncthreads();
  // phase7: LN1 -> Abf
  {
    int r=tid>>4, seg=tid&15;
    if(r<10){
      float s=0.f,q=0.f;
      #pragma unroll
      for(int j4=0;j4<4;j4++){
        float4 v=*(const float4*)&Vf[r][seg*16+j4*4];
        s+=v.x+v.y+v.z+v.w; q+=v.x*v.x+v.y*v.y+v.z*v.z+v.w*v.w;
      }
      s+=__shfl_xor(s,1); q+=__shfl_xor(q,1);
      s+=__shfl_xor(s,2); q+=__shfl_xor(q,2);
      s+=__shfl_xor(s,4); q+=__shfl_xor(q,4);
      s+=__shfl_xor(s,8); q+=__shfl_xor(q,8);
      float mean=s*(1.0f/256.0f), rstd=rsqrtf(q*(1.0f/256.0f)-mean*mean+1e-5f);
      #pragma unroll
      for(int j4=0;j4<4;j4++){
        int c=seg*16+j4*4;
        float4 v=*(const float4*)&Vf[r][c];
        unsigned short q0=bf16h((v.x-mean)*rstd*ln1g[c+0]+ln1b[c+0]);
        unsigned short q1=bf16h((v.y-mean)*rstd*ln1g[c+1]+ln1b[c+1]);
        unsigned short q2=bf16h((v.z-mean)*rstd*ln1g[c+2]+ln1b[c+2]);
        unsigned short q3=bf16h((v.w-mean)*rstd*ln1g[c+3]+ln1b[c+3]);
        *(uint2*)&Abf[r][c]=make_uint2((unsigned)q0|((unsigned)q1<<16),(unsigned)q2|((unsigned)q3<<16));
      }
    } else {
      #pragma unroll
      for(int j4=0;j4<4;j4++) *(uint2*)&Abf[r][seg*16+j4*4]=make_uint2(0,0);
    }
  }
  __syncthreads();
  // phase8: glu1 -> Hb (masked)
  {
    ffrag aa[4],ag[4];
    #pragma unroll
    for(int j=0;j<4;j++){aa[j][0]=0;aa[j][1]=0;aa[j][2]=0;aa[j][3]=0;
                         ag[j][0]=0;ag[j][1]=0;ag[j][2]=0;ag[j][3]=0;}
    #pragma unroll
    for(int kt=0;kt<8;kt++){
      bfrag af=*(const bfrag*)&Abf[lm][kt*32+lq*8];
      #pragma unroll
      for(int j=0;j<4;j++){
        int nta=w*4+j, ntg=nta+16;
        bfrag bfa=*(const bfrag*)(wb+PK_GLU1+((((unsigned)(nta*8+kt))*64u+(unsigned)lane)<<3));
        bfrag bfg=*(const bfrag*)(wb+PK_GLU1+((((unsigned)(ntg*8+kt))*64u+(unsigned)lane)<<3));
        aa[j]=__builtin_amdgcn_mfma_f32_16x16x32_bf16(af,bfa,aa[j],0,0,0);
        ag[j]=__builtin_amdgcn_mfma_f32_16x16x32_bf16(af,bfg,ag[j],0,0,0);
      }
    }
    __syncthreads();
    #pragma unroll
    for(int j=0;j<4;j++){
      int n=w*64+j*16+lm;
      float ba=g1b[n], bg=g1b[n+256];
      #pragma unroll
      for(int reg=0;reg<4;reg++){
        int row=lq*4+reg;
        float a=aa[j][reg]+ba, g=ag[j][reg]+bg;
        float hv=a*(1.0f/(1.0f+__expf(-g)));
        if(row>=10||tmL[row+1]!=0.0f) hv=0.0f;
        Hb[row][n]=bf16h(hv);
      }
    }
  }
  __syncthreads();
  // phase9: dwconv1 -> Abf rows 0..7
  {
    float w0=dws[1][0][tid],w1=dws[1][1][tid],w2=dws[1][2][tid];
    for(int r=0;r<8;r++){
      float a=w0*bf2f(Hb[r][tid])+w1*bf2f(Hb[r+1][tid])+w2*bf2f(Hb[r+2][tid]);
      Abf[r][tid]=bf16h(a);
    }
    for(int r=8;r<16;r++) Abf[r][tid]=0;
  }
  __syncthreads();
  // phase10: outproj1 + residual + mask -> V2 global
  {
    ffrag acc[4];
    #pragma unroll
    for(int j=0;j<4;j++){acc[j][0]=0;acc[j][1]=0;acc[j][2]=0;acc[j][3]=0;}
    #pragma unroll
    for(int kt=0;kt<8;kt++){
      bfrag af=*(const bfrag*)&Abf[lm][kt*32+lq*8];
      #pragma unroll
      for(int j=0;j<4;j++){
        int nt=w*4+j;
        bfrag bf=*(const bfrag*)(wb+PK_OUT1+((((unsigned)(nt*8+kt))*64u+(unsigned)lane)<<3));
        acc[j]=__builtin_amdgcn_mfma_f32_16x16x32_bf16(af,bf,acc[j],0,0,0);
      }
    }
    #pragma unroll
    for(int j=0;j<4;j++){
      int n=w*64+j*16+lm;
      float bn=o1b[n];
      #pragma unroll
      for(int reg=0;reg<4;reg++){
        int row=lq*4+reg;
        if(row<8){
          float v=(tmL[row+2]!=0.0f)? 0.0f : acc[j][reg]+bn+Vf[row+1][n];
          V2[(unsigned)(b*256+s0+row)*256u+n]=v;
        }
      }
    }
  }
}

// ---------------- duration head (fp32, exact) ----------------
__global__ __launch_bounds__(256) void k_dur(const float* __restrict__ V2, const float* __restrict__ p1w,
    const float* __restrict__ p1b, const float* __restrict__ sdo, const float* __restrict__ rhythm,
    float* __restrict__ ws, float* __restrict__ outp){
  __shared__ float p1[HH];
  __shared__ float sd[SS];
  __shared__ float red[16];
  int b=blockIdx.x, tid=threadIdx.x;
  int wid=tid>>6, lane=tid&63;
  p1[tid]=p1w[tid];
  __syncthreads();
  float accd=p1b[0];
  const float* row=V2+(unsigned)(b*SS+tid)*HH;
  for(int k=0;k<HH;k+=4){
    float4 v=*(const float4*)&row[k];
    accd+=v.x*p1[k]+v.y*p1[k+1]+v.z*p1[k+2]+v.w*p1[k+3];
  }
  float Dv=fmaxf(accd,0.0f)+log1pf(expf(-fabsf(accd)));
  if(ws[WS_TMASK+b*SS+tid]!=0.0f) Dv=0.0f;
  float sv=sdo[b*SS+tid];
  float a=Dv, c=sv;
  for(int off=32;off;off>>=1){ a+=__shfl_down(a,off); c+=__shfl_down(c,off); }
  if(lane==0){ red[wid]=a; red[wid+8]=c; }
  __syncthreads();
  float Dsum=red[0]+red[1]+red[2]+red[3];
  float pred=red[8]+red[9]+red[10]+red[11];
  float al=(pred/rhythm[b])/Dsum;
  float sDv=al*Dv;
  sd[tid]=sDv;
  __syncthreads();
  for(int off=1;off<SS;off<<=1){
    float t=(tid>=off)?sd[tid-off]:0.0f;
    __syncthreads();
    sd[tid]+=t;
    __syncthreads();
  }
  float ek=sd[tid], sk=ek-sDv;
  ws[WS_EK+b*SS+tid]=ek;
  ws[WS_SK+b*SS+tid]=sk;
  float melf=sd[SS-1];
  int mel=(int)rintf(melf); mel=mel<1?1:(mel>MLEN?MLEN:mel);
  if(tid==0){
    ws[WS_ALPHA+b]=al;
    ((int*)ws)[WS_MELI+b]=mel;
    outp[OUT_ALPHA+b]=al;
    outp[OUT_MLEN+b]=(float)mel;
  }
  for(int t=tid;t<MLEN;t+=SS) outp[OUT_MMASK+b*MLEN+t]=(t>=mel)?1.0f:0.0f;
}

// ---------------- post: T2 (0..255) | cv (256..383) | cp (384..391) ----------------
__global__ __launch_bounds__(256) void k_post(const float* __restrict__ V2,
    const unsigned short* __restrict__ wbp2, const float* __restrict__ p2b,
    const float* __restrict__ cwk, const float* __restrict__ cwb,
    const float* __restrict__ cwg, const float* __restrict__ cwbe,
    const float* __restrict__ mkb1k, const float* __restrict__ mkb1b,
    float* __restrict__ ws){
  int bx=blockIdx.x, tid=threadIdx.x;
  if(bx<256){
    __shared__ unsigned short Abf[18][264];
    int m0=(bx>>1)*16, nh=bx&1, b=m0>>8, s0=m0&255;
    for(int it=0;it<18;it++){
      int sI=s0-1+it;
      float v=(sI>=0&&sI<256)? V2[(unsigned)(b*256+sI)*256u+tid] : 0.0f;
      Abf[it][tid]=bf16h(v);
    }
    __syncthreads();
    int w=tid>>6, lane=tid&63, lq=lane>>4, lm=lane&15;
    ffrag acc[2];
    #pragma unroll
    for(int tt=0;tt<2;tt++){ acc[tt][0]=0;acc[tt][1]=0;acc[tt][2]=0;acc[tt][3]=0; }
    for(int k3=0;k3<3;k3++){
      const unsigned short* wb3=wbp2+(unsigned)k3*65536u;
      #pragma unroll
      for(int kt=0;kt<8;kt++){
        bfrag af=*(const bfrag*)&Abf[lm+k3][kt*32+lq*8];
        #pragma unroll
        for(int tt=0;tt<2;tt++){
          int nt=nh*8+w*2+tt;
          bfrag bf=*(const bfrag*)(wb3+((((unsigned)(nt*8+kt))*64u+(unsigned)lane)<<3));
          acc[tt]=__builtin_amdgcn_mfma_f32_16x16x32_bf16(af,bf,acc[tt],0,0,0);
        }
      }
    }
    float al=ws[WS_ALPHA+b];
    unsigned short* stt=(unsigned short*)(ws+WS_STT);
    #pragma unroll
    for(int tt=0;tt<2;tt++){
      int n=nh*128+w*32+tt*16+lm;
      float bn=p2b[n];
      unsigned short o0=bf16h((acc[tt][0]+bn)*al);
      unsigned short o1=bf16h((acc[tt][1]+bn)*al);
      unsigned short o2=bf16h((acc[tt][2]+bn)*al);
      unsigned short o3=bf16h((acc[tt][3]+bn)*al);
      *(uint2*)&stt[((unsigned)(b*256+n)<<8)+(unsigned)(s0+lq*4)]=
        make_uint2((unsigned)o0|((unsigned)o1<<16),(unsigned)o2|((unsigned)o3<<16));
    }
  } else if(bx<384){
    __shared__ float Vt[18][SS];
    int bb=bx-256;
    int b=bb>>4, tile=bb&15;
    int sbase=tile*16;
    float al=ws[WS_ALPHA+b];
    for(int rr=0;rr<18;rr++){
      int s=sbase-1+rr;
      Vt[rr][tid]=(s>=0&&s<SS)?al*V2[(b*SS+s)*HH+tid]:0.0f;
    }
    __syncthreads();
    int sl=tid>>4, oc=tid&15;
    float a0=cwb[oc],a1=0.f,a2=0.f,a3=0.f;
    for(int k3=0;k3<3;k3++){
      const float* vp=&Vt[sl+k3][0];
      const float* wpp=cwk+(unsigned)k3*HH*CWW+oc;
      for(int c=0;c<HH;c+=4){
        a0+=vp[c+0]*wpp[(c+0)*CWW];
        a1+=vp[c+1]*wpp[(c+1)*CWW];
        a2+=vp[c+2]*wpp[(c+2)*CWW];
        a3+=vp[c+3]*wpp[(c+3)*CWW];
      }
    }
    float acc=fmaxf((a0+a1)+(a2+a3),0.0f);
    float ssum=acc, qsum=acc*acc;
    for(int off=8;off;off>>=1){ ssum+=__shfl_xor(ssum,off); qsum+=__shfl_xor(qsum,off); }
    float mean=ssum*(1.0f/CWW), var=qsum*(1.0f/CWW)-mean*mean;
    float cv=(acc-mean)*rsqrtf(var+1e-5f)*cwg[oc]+cwbe[oc];
    ws[WS_CV+(unsigned)(b*SS+sbase+sl)*CWW+oc]=cv;
  } else {
    __shared__ float CvL[258][17];
    __shared__ float k1c[3][3][CWW][NOC];
    __shared__ float kab[3][3][2][NOC];
    __shared__ float skE[258], ekE[258], fiE[258];
    int b=bx-384;
    for(int i=tid;i<3*3*CWW*NOC;i+=256){
      int oc=i&15, ic=(i>>4)&15, kk=i>>8;
      int kw=kk%3, kh=kk/3;
      k1c[kh][kw][ic][oc]=mkb1k[((kh*3+kw)*18+2+ic)*NOC+oc];
    }
    for(int i=tid;i<3*3*2*NOC;i+=256){
      int oc=i&15, ch=(i>>4)&1, kk=i>>5;
      int kw=kk%3, kh=kk/3;
      kab[kh][kw][ch][oc]=mkb1k[((kh*3+kw)*18+ch)*NOC+oc];
    }
    for(int i=tid;i<SS*CWW;i+=256) CvL[1+(i>>4)][i&15]=ws[WS_CV+(unsigned)b*SS*CWW+i];
    if(tid<CWW){ CvL[0][tid]=0.f; CvL[257][tid]=0.f; }
    if(tid<258){
      float sk=0.f, ek=0.f, fi=0.f;
      if(tid>=1 && tid<=SS){
        sk=ws[WS_SK+b*SS+tid-1];
        ek=ws[WS_EK+b*SS+tid-1];
        fi=(ws[WS_TMASK+b*SS+tid-1]!=0.0f)?0.0f:1.0f;
      }
      skE[tid]=sk; ekE[tid]=ek; fiE[tid]=fi;
    }
    __syncthreads();
    float* cpg=ws+WS_CP+(unsigned)b*3*SS*NOC;
    float ccv[16],ssv[16],cci[16],ssi[16];
    #pragma unroll
    for(int oc=0;oc<NOC;oc++){ float bb2=mkb1b[oc]; ccv[oc]=bb2; cci[oc]=bb2; ssv[oc]=0.f; ssi[oc]=0.f; }
    for(int dt=0;dt<3;dt++){
      float acc[NOC];
      #pragma unroll
      for(int oc=0;oc<NOC;oc++) acc[oc]=0.f;
      #pragma unroll
      for(int ds=0;ds<3;ds++){
        #pragma unroll
        for(int ic=0;ic<CWW;ic++){
          float v=CvL[tid+ds][ic];
          #pragma unroll
          for(int oc=0;oc<NOC;oc++) acc[oc]+=v*k1c[dt][ds][ic][oc];
        }
      }
      for(int oc=0;oc<NOC;oc++) cpg[(unsigned)(dt*SS+tid)*NOC+oc]=acc[oc];
      float va[16],vb[16],ia[16],ib2[16];
      #pragma unroll
      for(int oc=0;oc<NOC;oc++){ va[oc]=0.f; vb[oc]=0.f; ia[oc]=0.f; ib2[oc]=0.f; }
      #pragma unroll
      for(int ds=0;ds<3;ds++){
        int j=tid+ds;
        float inb=(j>=1&&j<=SS)?1.0f:0.0f;
        float fb=fiE[j];
        float skv=skE[j], ekv=ekE[j];
        #pragma unroll
        for(int oc=0;oc<NOC;oc++){
          float ka=kab[dt][ds][0][oc], kb=kab[dt][ds][1][oc];
          float d=ka-kb, e=kb*ekv-ka*skv;
          va[oc]+=inb*d; vb[oc]+=inb*e; ia[oc]+=fb*d; ib2[oc]+=fb*e;
        }
      }
      float dtf=(float)dt;
      #pragma unroll
      for(int oc=0;oc<NOC;oc++){
        ccv[oc]+=acc[oc]+vb[oc]+dtf*va[oc]; ssv[oc]+=va[oc];
        cci[oc]+=acc[oc]+ib2[oc]+dtf*ia[oc]; ssi[oc]+=ia[oc];
      }
    }
    unsigned base=(unsigned)(b*SS+tid)*16u;
    for(int oc=0;oc<NOC;oc++){
      ws[WS_CCV+base+oc]=ccv[oc];
      ws[WS_SSV+base+oc]=ssv[oc];
      ws[WS_CCI+base+oc]=cci[oc];
      ws[WS_SSI+base+oc]=ssi[oc];
    }
  }
}

// ---------------- stage B: conv1 -> conv2(MFMA) -> softmax -> Wmat ----------------
__global__ __launch_bounds__(256,4) void k_stageB(
    const float* __restrict__ ws, const float* __restrict__ mkb1k, const float* __restrict__ mkb1b,
    const float* __restrict__ mkb2k, const float* __restrict__ mkb2b,
    const float* __restrict__ lww, const float* __restrict__ lwb,
    float* __restrict__ outp){
  __shared__ short ringh[3][258][RB];
  __shared__ float skL[258], ekL[258];
  __shared__ unsigned char finC[260];
  __shared__ __align__(16) float wscL[SS];
  __shared__ float red[16];
  int bx=blockIdx.x, b=bx/125, chunk=bx%125, t0=chunk*8, tid=threadIdx.x;
  int wid=tid>>6, lane=tid&63;
  int lq=lane>>4, lm=lane&15;
  if(tid<258){
    float sk=0.f, ek=0.f; unsigned char fin=0;
    if(tid>=1 && tid<=SS){
      sk=ws[WS_SK+b*SS+tid-1];
      ek=ws[WS_EK+b*SS+tid-1];
      fin=(ws[WS_TMASK+b*SS+tid-1]!=0.0f)?0:1;
    }
    skL[tid]=sk; ekL[tid]=ek; finC[tid]=fin;
  }
  if(tid<72){
    int sl=tid/24, rem=tid%24;
    int row=(rem<12)?0:257, c=(rem%12)*2;
    *(int*)&ringh[sl][row][c]=0;
  }
  int mel=((const int*)ws)[WS_MELI+b];
  __syncthreads();

  const float* cpb=ws+WS_CP+(unsigned)b*3*SS*NOC;

  unsigned offA[5]; int dtL[5], zgL[5];
  bfrag bfw[5];
  {
    #pragma unroll
    for(int i=0;i<5;i++){
      int g=4*i+lq;
      int dt,ds,hf,zg;
      if(g<18){ dt=g/6; int rm=g-6*dt; ds=rm>>1; hf=rm&1; zg=0; }
      else { dt=0; ds=0; hf=0; zg=1; }
      int srow=wid*64+lm+ds;
      offA[i]=(unsigned)((srow*RB+8*hf)*2);
      dtL[i]=dt; zgL[i]=zg;
      int pk[4];
      if(!zg){
        #pragma unroll
        for(int j=0;j<4;j++){
          unsigned u0=bf16rne(mkb2k[(8*g+2*j)*NOC+lm]);
          unsigned u1=bf16rne(mkb2k[(8*g+2*j+1)*NOC+lm]);
          pk[j]=(int)((u0>>16)|(u1&0xffff0000u));
        }
      } else pk[0]=pk[1]=pk[2]=pk[3]=0;
      bfw[i]=__builtin_bit_cast(bfrag, make_int4(pk[0],pk[1],pk[2],pk[3]));
    }
  }
  float b2v=mkb2b[lm];
  float lwwv=lww[lm];
  float lwb0=lwb[0];
  const char* ringB=(const char*)&ringh[0][0][0];
  bfrag azero={};

  auto conv1row=[&](int T){
    int s=tid;
    float acc[NOC];
    bool fv=(T>=1)&&(T<=998)&&(T+1<mel);
    bool fi=(T>=2)&&(T<=998)&&(T-1>=mel);
    if(fv||fi){
      const float* cc=ws+(fv?WS_CCV:WS_CCI)+(unsigned)(b*SS+s)*16u;
      const float* s2=ws+(fv?WS_SSV:WS_SSI)+(unsigned)(b*SS+s)*16u;
      float Tf=(float)T;
      #pragma unroll
      for(int q=0;q<4;q++){
        float4 c4=((const float4*)cc)[q];
        float4 s4=((const float4*)s2)[q];
        acc[4*q+0]=c4.x+Tf*s4.x; acc[4*q+1]=c4.y+Tf*s4.y;
        acc[4*q+2]=c4.z+Tf*s4.z; acc[4*q+3]=c4.w+Tf*s4.w;
      }
    } else {
      #pragma unroll
      for(int oc=0;oc<NOC;oc++) acc[oc]=mkb1b[oc];
      #pragma unroll
      for(int dt=0;dt<3;dt++){
        int tr=T+dt-1;
        if(tr<0||tr>=MLEN) continue;
        bool valid=(tr<mel);
        float tt=(float)(tr+1);
        float gg[3], hh[3];
        #pragma unroll
        for(int ds=0;ds<3;ds++){
          int j=s+ds;
          float f = valid ? ((j>=1&&j<=SS)?1.0f:0.0f) : (float)finC[j];
          gg[ds]=f*(tt-skL[j]);
          hh[ds]=f*(ekL[j]-tt);
        }
        const float* cpr=cpb+(unsigned)(dt*SS+s)*NOC;
        float4 c0=((const float4*)cpr)[0], c1=((const float4*)cpr)[1];
        float4 c2=((const float4*)cpr)[2], c3=((const float4*)cpr)[3];
        acc[0]+=c0.x; acc[1]+=c0.y; acc[2]+=c0.z; acc[3]+=c0.w;
        acc[4]+=c1.x; acc[5]+=c1.y; acc[6]+=c1.z; acc[7]+=c1.w;
        acc[8]+=c2.x; acc[9]+=c2.y; acc[10]+=c2.z; acc[11]+=c2.w;
        acc[12]+=c3.x; acc[13]+=c3.y; acc[14]+=c3.z; acc[15]+=c3.w;
        #pragma unroll
        for(int ds=0;ds<3;ds++){
          const float* kA=mkb1k+((dt*3+ds)*18+0)*NOC;
          const float* kB=mkb1k+((dt*3+ds)*18+1)*NOC;
          #pragma unroll
          for(int oc=0;oc<NOC;oc++) acc[oc]+=gg[ds]*kA[oc]+hh[ds]*kB[oc];
        }
      }
    }
    int slot=T%3;
    int pk[8];
    #pragma unroll
    for(int j=0;j<8;j++){
      float x0=acc[2*j], x1=acc[2*j+1];
      float s0=x0/(1.0f+__expf(-x0));
      float s1=x1/(1.0f+__expf(-x1));
      unsigned u0=bf16rne(s0), u1=bf16rne(s1);
      pk[j]=(int)((u0>>16)|(u1&0xffff0000u));
    }
    int4* dst=(int4*)&ringh[slot][s+1][0];
    dst[0]=make_int4(pk[0],pk[1],pk[2],pk[3]);
    dst[1]=make_int4(pk[4],pk[5],pk[6],pk[7]);
  };

  if(t0>0) conv1row(t0-1);
  conv1row(t0);

  #pragma unroll 1
  for(int r=0;r<8;r++){
    int t=t0+r;
    if(t+1<MLEN) conv1row(t+1);
    __syncthreads();
    int tmod=t%3;
    ffrag acc2[4];
    #pragma unroll
    for(int tt=0;tt<4;tt++){ acc2[tt][0]=b2v; acc2[tt][1]=b2v; acc2[tt][2]=b2v; acc2[tt][3]=b2v; }
    #pragma unroll
    for(int i=0;i<5;i++){
      int dt=dtL[i];
      int x=tmod+dt+2; x=(x>=3)?x-3:x; x=(x>=3)?x-3:x;
      int tr=t+dt-1;
      bool av=((unsigned)tr<(unsigned)MLEN)&&(!zgL[i]);
      const char* rp=ringB+(unsigned)x*(258u*RB*2u)+offA[i];
      #pragma unroll
      for(int tt=0;tt<4;tt++){
        int4 ra=*(const int4*)(rp+tt*(16*RB*2));
        bfrag a=av?__builtin_bit_cast(bfrag,ra):azero;
        acc2[tt]=__builtin_amdgcn_mfma_f32_16x16x32_bf16(a,bfw[i],acc2[tt],0,0,0);
      }
    }
    #pragma unroll
    for(int tt=0;tt<4;tt++){
      float out4[4];
      #pragma unroll
      for(int q=0;q<4;q++){
        float xx=acc2[tt][q];
        float pv=(xx/(1.0f+__expf(-xx)))*lwwv;
        pv+=__shfl_xor(pv,1); pv+=__shfl_xor(pv,2); pv+=__shfl_xor(pv,4); pv+=__shfl_xor(pv,8);
        out4[q]=pv+lwb0;
      }
      if(lm==0){
        *(float4*)&wscL[wid*64+tt*16+lq*4]=make_float4(out4[0],out4[1],out4[2],out4[3]);
      }
    }
    __syncthreads();
    float fm=(float)finC[tid+1];
    float wsc=wscL[tid];
    float val=(fm!=0.0f)?wsc:-3.0e38f;
    float mx=val;
    for(int off=32;off;off>>=1) mx=fmaxf(mx,__shfl_down(mx,off));
    if(lane==0) red[wid]=mx;
    __syncthreads();
    mx=fmaxf(fmaxf(red[0],red[1]),fmaxf(red[2],red[3]));
    float e=(fm!=0.0f)?__expf(wsc-mx):0.0f;
    float sm=e;
    for(int off=32;off;off>>=1) sm+=__shfl_down(sm,off);
    if(lane==0) red[8+wid]=sm;
    __syncthreads();
    sm=red[8]+red[9]+red[10]+red[11];
    outp[OUT_W+(unsigned)(b*MLEN+t)*SS+tid]=e/sm;
    __syncthreads();
  }
}

// ---------------- up = W @ sT (MFMA) + LN + mel mask ----------------
__global__ __launch_bounds__(256) void k_up(const float* __restrict__ ws,
    const float* __restrict__ lng, const float* __restrict__ lnb, float* __restrict__ outp){
  __shared__ unsigned short Wbf[16][264];
  __shared__ float UpL[16][264];
  __shared__ float gb[2][256];
  int bx=blockIdx.x, b=bx/63, tile=bx%63, t0=tile*16, tid=threadIdx.x;
  gb[0][tid]=lng[tid]; gb[1][tid]=lnb[tid];
  for(int it=0;it<16;it++){
    int t=t0+it;
    float v=(t<MLEN)? outp[OUT_W+(unsigned)(b*MLEN+t)*256u+tid] : 0.0f;
    Wbf[it][tid]=bf16h(v);
  }
  int mel=((const int*)ws)[WS_MELI+b];
  __syncthreads();
  int w=tid>>6, lane=tid&63, lq=lane>>4, lm=lane&15;
  const unsigned short* stt=(const unsigned short*)(ws+WS_STT)+(unsigned)b*65536u;
  ffrag acc[4];
  #pragma unroll
  for(int tt=0;tt<4;tt++){ acc[tt][0]=0;acc[tt][1]=0;acc[tt][2]=0;acc[tt][3]=0; }
  #pragma unroll
  for(int kt=0;kt<8;kt++){
    bfrag af=*(const bfrag*)&Wbf[lm][kt*32+lq*8];
    #pragma unroll
    for(int tt=0;tt<4;tt++){
      int n=w*64+tt*16+lm;
      bfrag bf=*(const bfrag*)(stt+((unsigned)n<<8)+(unsigned)(kt*32+lq*8));
      acc[tt]=__builtin_amdgcn_mfma_f32_16x16x32_bf16(af,bf,acc[tt],0,0,0);
    }
  }
  #pragma unroll
  for(int tt=0;tt<4;tt++){
    #pragma unroll
    for(int reg=0;reg<4;reg++)
      UpL[lq*4+reg][w*64+tt*16+lm]=acc[tt][reg];
  }
  __syncthreads();
  int r=tid>>4, seg=tid&15;
  float s=0.f,q=0.f;
  #pragma unroll
  for(int j4=0;j4<4;j4++){
    float4 v=*(const float4*)&UpL[r][seg*16+j4*4];
    s+=v.x+v.y+v.z+v.w; q+=v.x*v.x+v.y*v.y+v.z*v.z+v.w*v.w;
  }
  s+=__shfl_xor(s,1); q+=__shfl_xor(q,1);
  s+=__shfl_xor(s,2); q+=__shfl_xor(q,2);
  s+=__shfl_xor(s,4); q+=__shfl_xor(q,4);
  s+=__shfl_xor(s,8); q+=__shfl_xor(q,8);
  float mean=s*(1.0f/256.0f), rstd=rsqrtf(q*(1.0f/256.0f)-mean*mean+1e-5f);
  int t=t0+r;
  if(t<MLEN){
    bool vld=(t<mel);
    #pragma unroll
    for(int j4=0;j4<4;j4++){
      int c=seg*16+j4*4;
      float4 v=*(const float4*)&UpL[r][c];
      float4 o;
      o.x=vld?((v.x-mean)*rstd*gb[0][c+0]+gb[1][c+0]):0.0f;
      o.y=vld?((v.y-mean)*rstd*gb[0][c+1]+gb[1][c+1]):0.0f;
      o.z=vld?((v.z-mean)*rstd*gb[0][c+2]+gb[1][c+2]):0.0f;
      o.w=vld?((v.w-mean)*rstd*gb[0][c+3]+gb[1][c+3]):0.0f;
      *(float4*)&outp[OUT_UP+(unsigned)(b*MLEN+t)*256u+c]=o;
    }
  }
}

extern "C" void kernel_launch(void* const* d_in, const int* in_sizes, int n_in,
                              void* d_out, int out_size, void* d_ws, size_t ws_size,
                              hipStream_t stream){
  const float* ce   =(const float*)d_in[0];
  const float* spk  =(const float*)d_in[1];
  const float* rhy  =(const float*)d_in[2];
  const float* sdo  =(const float*)d_in[3];
  const void*  tmr  =d_in[4];
  const float* in_w =(const float*)d_in[5];
  const float* in_b =(const float*)d_in[6];
  const float* l0lg =(const float*)d_in[7];
  const float* l0lb =(const float*)d_in[8];
  const float* l0gw =(const float*)d_in[9];
  const float* l0gb =(const float*)d_in[10];
  const float* l0dw =(const float*)d_in[11];
  const float* l0ow =(const float*)d_in[12];
  const float* l0ob =(const float*)d_in[13];
  const float* l1lg =(const float*)d_in[14];
  const float* l1lb =(const float*)d_in[15];
  const float* l1gw =(const float*)d_in[16];
  const float* l1gb =(const float*)d_in[17];
  const float* l1dw =(const float*)d_in[18];
  const float* l1ow =(const float*)d_in[19];
  const float* l1ob =(const float*)d_in[20];
  const float* p1w  =(const float*)d_in[21];
  const float* p1b  =(const float*)d_in[22];
  const float* p2k  =(const float*)d_in[23];
  const float* p2b  =(const float*)d_in[24];
  const float* cwk  =(const float*)d_in[25];
  const float* cwb  =(const float*)d_in[26];
  const float* cwg  =(const float*)d_in[27];
  const float* cwbe =(const float*)d_in[28];
  const float* m1k  =(const float*)d_in[29];
  const float* m1b  =(const float*)d_in[30];
  const float* m2k  =(const float*)d_in[31];
  const float* m2b  =(const float*)d_in[32];
  const float* lww  =(const float*)d_in[33];
  const float* lwbp =(const float*)d_in[34];
  const float* lng  =(const float*)d_in[35];
  const float* lnb  =(const float*)d_in[36];
  float* ws=(float*)d_ws;
  float* outp=(float*)d_out;
  const unsigned short* wbb=(const unsigned short*)(ws+WS_WB);

  k_prepmask<<<257,256,0,stream>>>(tmr, in_w, l0gw, l1gw, l0ow, l1ow, p2k, ws);
  k_front   <<<256,256,0,stream>>>(ce, spk, wbb, in_b,
                                   l0gb, l0lg, l0lb, l0dw, l0ob,
                                   l1gb, l1lg, l1lb, l1dw, l1ob,
                                   ws+WS_TMASK, ws+WS_V2);
  k_dur     <<<8,256,0,stream>>>(ws+WS_V2, p1w, p1b, sdo, rhy, ws, outp);
  k_post    <<<392,256,0,stream>>>(ws+WS_V2, wbb+PK_P2, p2b, cwk, cwb, cwg, cwbe, m1k, m1b, ws);
  k_stageB  <<<1000,256,0,stream>>>(ws, m1k, m1b, m2k, m2b, lww, lwbp, outp);
  k_up      <<<504,256,0,stream>>>(ws, lng, lnb, outp);
}